// Round 11
// baseline (1808.982 us; speedup 1.0000x reference)
//
#include <hip/hip_runtime.h>
#include <hip/hip_bf16.h>
#include <math.h>

typedef __hip_bfloat16 bf16;
typedef __attribute__((ext_vector_type(8))) short short8;
typedef __attribute__((ext_vector_type(4))) float f32x4;

#define DEPTH 6
#define DM    512
#define NH    8
#define DH    64
#define DFF   2048
#define TSEQ  2048
#define BATCH 2
#define ROWS  (BATCH*TSEQ)   // 4096
#define NVOCAB 256

// q3 region layout (elements): Q [4096*512] | K [4096*512] | Vt [16][64][2048]
#define Q3_K_OFF  2097152
#define Q3_VT_OFF 4194304

constexpr size_t SZ_QKV  = (size_t)DEPTH * 3 * DM * DM;   // 4718592
constexpr size_t SZ_PROJ = (size_t)DEPTH * DM * DM;       // 1572864
constexpr size_t SZ_FC1  = (size_t)DEPTH * DFF * DM;      // 6291456
constexpr size_t SZ_FC2  = SZ_FC1;
constexpr size_t SZ_HEAD = (size_t)NVOCAB * DM;           // 131072
constexpr size_t SZ_ALL  = SZ_QKV + SZ_PROJ + SZ_FC1 + SZ_FC2 + SZ_HEAD;

// async global->LDS, 16 B per lane; LDS dest must be wave-uniform base + lane*16
#define GLDS(gp, lp) __builtin_amdgcn_global_load_lds( \
    (const __attribute__((address_space(1))) void*)(gp), \
    (__attribute__((address_space(3))) void*)(lp), 16, 0, 0)

__device__ __forceinline__ short f2bs(float x) {
    union { bf16 b; short s; } u; u.b = __float2bfloat16(x); return u.s;
}

// ------------- all weights fp32 -> bf16 (single dispatch, contiguous dst) -----------
__global__ __launch_bounds__(256) void w2b_all(const float* __restrict__ q,
    const float* __restrict__ p, const float* __restrict__ f1,
    const float* __restrict__ f2, const float* __restrict__ hw, bf16* __restrict__ dst)
{
    size_t i = ((size_t)blockIdx.x * 256 + threadIdx.x) * 8;
    const float* s; size_t off;
    if      (i < SZ_QKV)                               { s = q;  off = 0; }
    else if (i < SZ_QKV + SZ_PROJ)                     { s = p;  off = SZ_QKV; }
    else if (i < SZ_QKV + SZ_PROJ + SZ_FC1)            { s = f1; off = SZ_QKV + SZ_PROJ; }
    else if (i < SZ_QKV + SZ_PROJ + SZ_FC1 + SZ_FC2)   { s = f2; off = SZ_QKV + SZ_PROJ + SZ_FC1; }
    else                                               { s = hw; off = SZ_QKV + SZ_PROJ + SZ_FC1 + SZ_FC2; }
    float4 f0 = *(const float4*)(s + (i - off));
    float4 f1v = *(const float4*)(s + (i - off) + 4);
    short8 o;
    o[0] = f2bs(f0.x); o[1] = f2bs(f0.y); o[2] = f2bs(f0.z); o[3] = f2bs(f0.w);
    o[4] = f2bs(f1v.x); o[5] = f2bs(f1v.y); o[6] = f2bs(f1v.z); o[7] = f2bs(f1v.w);
    *(short8*)((short*)dst + i) = o;
}

// ------------- embedding ------------------------------------------------------------
__global__ __launch_bounds__(256) void emb_kernel(const int* __restrict__ x,
    const float* __restrict__ tok, const float* __restrict__ pos, float* __restrict__ h)
{
    int i = blockIdx.x * 256 + threadIdx.x;
    int d = i & (DM - 1);
    int r = i >> 9;
    int t = r & (TSEQ - 1);
    h[i] = tok[x[r] * DM + d] + pos[t * DM + d];
}

// ------------- layernorm: wave per row, fp32 in, bf16 out ---------------------------
__global__ __launch_bounds__(256) void ln_kernel(const float* __restrict__ x,
    const float* __restrict__ w, const float* __restrict__ b, bf16* __restrict__ out)
{
    int row = blockIdx.x * 4 + (threadIdx.x >> 6);
    int lane = threadIdx.x & 63;
    const float* xr = x + (size_t)row * DM;

    float4 v0 = *(const float4*)(xr + lane * 4);
    float4 v1 = *(const float4*)(xr + 256 + lane * 4);

    float s = v0.x + v0.y + v0.z + v0.w + v1.x + v1.y + v1.z + v1.w;
    #pragma unroll
    for (int m = 1; m < 64; m <<= 1) s += __shfl_xor(s, m, 64);
    float mu = s * (1.f / DM);

    float var = (v0.x-mu)*(v0.x-mu) + (v0.y-mu)*(v0.y-mu) + (v0.z-mu)*(v0.z-mu)
              + (v0.w-mu)*(v0.w-mu) + (v1.x-mu)*(v1.x-mu) + (v1.y-mu)*(v1.y-mu)
              + (v1.z-mu)*(v1.z-mu) + (v1.w-mu)*(v1.w-mu);
    #pragma unroll
    for (int m = 1; m < 64; m <<= 1) var += __shfl_xor(var, m, 64);
    float rstd = rsqrtf(var * (1.f / DM) + 1e-5f);

    float4 w0 = *(const float4*)(w + lane * 4);
    float4 w1 = *(const float4*)(w + 256 + lane * 4);
    float4 b0 = *(const float4*)(b + lane * 4);
    float4 b1 = *(const float4*)(b + 256 + lane * 4);

    short4 o0, o1;
    o0.x = f2bs((v0.x - mu) * rstd * w0.x + b0.x);
    o0.y = f2bs((v0.y - mu) * rstd * w0.y + b0.y);
    o0.z = f2bs((v0.z - mu) * rstd * w0.z + b0.z);
    o0.w = f2bs((v0.w - mu) * rstd * w0.w + b0.w);
    o1.x = f2bs((v1.x - mu) * rstd * w1.x + b1.x);
    o1.y = f2bs((v1.y - mu) * rstd * w1.y + b1.y);
    o1.z = f2bs((v1.z - mu) * rstd * w1.z + b1.z);
    o1.w = f2bs((v1.w - mu) * rstd * w1.w + b1.w);
    *(short4*)(out + (size_t)row * DM + lane * 4) = o0;
    *(short4*)(out + (size_t)row * DM + 256 + lane * 4) = o1;
}

// ------------- MFMA GEMM 128x128: C = A(bf16) * W^T; WT = bf16 (GLDS) or fp32 -------
// EPI: 0 bf16 store, 1 fp32 +=, 2 GELU->bf16, 3 f32 store, 4 qkv split (Q|K|Vt)
template<int EPI, typename WT>
__global__ __launch_bounds__(256) void mfma_gemm(const bf16* __restrict__ A,
    const WT* __restrict__ W, void* __restrict__ Cv, int M, int N, int K)
{
    __shared__ short As[128 * 32];
    __shared__ short Bs[128 * 32];
    int tid = threadIdx.x;
    int bm0 = blockIdx.y * 128, bn0 = blockIdx.x * 128;
    int lane = tid & 63, w = tid >> 6;
    int wr = (w >> 1) * 64, wc = (w & 1) * 64;
    int fr = lane & 15, fk = (lane >> 4) * 8;

    f32x4 acc[4][4] = {};

    for (int k0 = 0; k0 < K; k0 += 32) {
        #pragma unroll
        for (int it = 0; it < 2; it++) {
            int c = it * 256 + tid;
            int row = c >> 2, kc = (c & 3) * 8;
            GLDS((const short*)A + (size_t)(bm0 + row) * K + k0 + kc, &As[c * 8]);
        }
        if constexpr (sizeof(WT) == 2) {
            #pragma unroll
            for (int it = 0; it < 2; it++) {
                int c = it * 256 + tid;
                int row = c >> 2, kc = (c & 3) * 8;
                GLDS((const short*)W + (size_t)(bn0 + row) * K + k0 + kc, &Bs[c * 8]);
            }
        } else {
            #pragma unroll
            for (int it = 0; it < 2; it++) {
                int c = it * 256 + tid;
                int row = c >> 2, kc = (c & 3) * 8;
                const float* wp = (const float*)W + (size_t)(bn0 + row) * K + k0 + kc;
                float4 f0 = *(const float4*)wp;
                float4 f1 = *(const float4*)(wp + 4);
                short8 p;
                p[0] = f2bs(f0.x); p[1] = f2bs(f0.y); p[2] = f2bs(f0.z); p[3] = f2bs(f0.w);
                p[4] = f2bs(f1.x); p[5] = f2bs(f1.y); p[6] = f2bs(f1.z); p[7] = f2bs(f1.w);
                *(short8*)&Bs[c * 8] = p;
            }
        }
        __syncthreads();

        short8 af[4], bfr[4];
        #pragma unroll
        for (int i = 0; i < 4; i++)
            af[i] = *(short8*)&As[(wr + i * 16 + fr) * 32 + fk];
        #pragma unroll
        for (int j = 0; j < 4; j++)
            bfr[j] = *(short8*)&Bs[(wc + j * 16 + fr) * 32 + fk];
        #pragma unroll
        for (int i = 0; i < 4; i++)
            #pragma unroll
            for (int j = 0; j < 4; j++)
                acc[i][j] = __builtin_amdgcn_mfma_f32_16x16x32_bf16(
                    af[i], bfr[j], acc[i][j], 0, 0, 0);
        __syncthreads();
    }

    int cr = (lane >> 4) * 4, cc = lane & 15;
    #pragma unroll
    for (int i = 0; i < 4; i++)
        #pragma unroll
        for (int j = 0; j < 4; j++)
            #pragma unroll
            for (int r = 0; r < 4; r++) {
                int m = bm0 + wr + i * 16 + cr + r;
                int n = bn0 + wc + j * 16 + cc;
                float v = acc[i][j][r];
                if (EPI == 4) {
                    // qkv split: Q | K row-major (stride 512), V transposed per head
                    short* q3s = (short*)Cv;
                    short sv = f2bs(v);
                    if (n < 512)
                        q3s[(size_t)m * 512 + n] = sv;
                    else if (n < 1024)
                        q3s[Q3_K_OFF + (size_t)m * 512 + (n - 512)] = sv;
                    else {
                        int bb = m >> 11, key = m & 2047;
                        int hd = (n - 1024) >> 6, dim = (n - 1024) & 63;
                        q3s[Q3_VT_OFF + (((size_t)(bb * 8 + hd) * 64 + dim) << 11) + key] = sv;
                    }
                } else {
                    size_t o = (size_t)m * N + n;
                    if (EPI == 0)      ((bf16*)Cv)[o] = __float2bfloat16(v);
                    else if (EPI == 1) ((float*)Cv)[o] += v;
                    else if (EPI == 2) ((bf16*)Cv)[o] =
                        __float2bfloat16(0.5f * v * (1.0f + erff(v * 0.70710678118654752f)));
                    else               ((float*)Cv)[o] = v;
                }
            }
}

// ------------- MFMA GEMM 128x64 (narrow N: proj/fc2/head), B row stride ldb ---------
template<int EPI, typename WT>
__global__ __launch_bounds__(256) void mfma_gemm_n64(const bf16* __restrict__ A,
    const WT* __restrict__ W, void* __restrict__ Cv, int M, int N, int K, int ldb)
{
    __shared__ short As[128 * 32];
    __shared__ short Bs[64 * 32];
    int tid = threadIdx.x;
    int bm0 = blockIdx.y * 128, bn0 = blockIdx.x * 64;
    int lane = tid & 63, w = tid >> 6;
    int wm = (w & 1) * 64, wn = (w >> 1) * 32;
    int fr = lane & 15, fk = (lane >> 4) * 8;

    f32x4 acc[4][2] = {};

    for (int k0 = 0; k0 < K; k0 += 32) {
        #pragma unroll
        for (int it = 0; it < 2; it++) {
            int c = it * 256 + tid;
            int row = c >> 2, kc = (c & 3) * 8;
            GLDS((const short*)A + (size_t)(bm0 + row) * K + k0 + kc, &As[c * 8]);
        }
        if constexpr (sizeof(WT) == 2) {
            int row = tid >> 2, kc = (tid & 3) * 8;
            GLDS((const short*)W + (size_t)(bn0 + row) * ldb + k0 + kc, &Bs[tid * 8]);
        } else {
            int row = tid >> 2, kc = (tid & 3) * 8;
            const float* wp = (const float*)W + (size_t)(bn0 + row) * ldb + k0 + kc;
            float4 f0 = *(const float4*)wp;
            float4 f1 = *(const float4*)(wp + 4);
            short8 p;
            p[0] = f2bs(f0.x); p[1] = f2bs(f0.y); p[2] = f2bs(f0.z); p[3] = f2bs(f0.w);
            p[4] = f2bs(f1.x); p[5] = f2bs(f1.y); p[6] = f2bs(f1.z); p[7] = f2bs(f1.w);
            *(short8*)&Bs[tid * 8] = p;
        }
        __syncthreads();

        short8 af[4], bfr[2];
        #pragma unroll
        for (int i = 0; i < 4; i++)
            af[i] = *(short8*)&As[(wm + i * 16 + fr) * 32 + fk];
        #pragma unroll
        for (int j = 0; j < 2; j++)
            bfr[j] = *(short8*)&Bs[(wn + j * 16 + fr) * 32 + fk];
        #pragma unroll
        for (int i = 0; i < 4; i++)
            #pragma unroll
            for (int j = 0; j < 2; j++)
                acc[i][j] = __builtin_amdgcn_mfma_f32_16x16x32_bf16(
                    af[i], bfr[j], acc[i][j], 0, 0, 0);
        __syncthreads();
    }

    int cr = (lane >> 4) * 4, cc = lane & 15;
    #pragma unroll
    for (int i = 0; i < 4; i++)
        #pragma unroll
        for (int j = 0; j < 2; j++)
            #pragma unroll
            for (int r = 0; r < 4; r++) {
                int m = bm0 + wm + i * 16 + cr + r;
                int n = bn0 + wn + j * 16 + cc;
                size_t o = (size_t)m * N + n;
                float v = acc[i][j][r];
                if (EPI == 0)      ((bf16*)Cv)[o] = __float2bfloat16(v);
                else if (EPI == 1) ((float*)Cv)[o] += v;
                else if (EPI == 2) ((bf16*)Cv)[o] =
                    __float2bfloat16(0.5f * v * (1.0f + erff(v * 0.70710678118654752f)));
                else               ((float*)Cv)[o] = v;
            }
}

// ------------- MFMA flash attention v3: barrier-free, fragments direct from L2 ------
// K rows and Vt rows are B-operand fragments in memory (16B contiguous per lane).
// No LDS staging, no __syncthreads; only the per-wave P C->A round-trip uses LDS.
__device__ __forceinline__ int pswz(int row, int col) {    // stride 136, 16-chunk perm
    return row * 136 + ((((col >> 3) + row) & 15) << 3) + (col & 7);
}

__global__ __launch_bounds__(256) void fattn_kernel(const short* __restrict__ q3,
    bf16* __restrict__ out)
{
    __shared__ __align__(16) short Ps[4][16 * 136];  // per-wave P strip

    int tid = threadIdx.x;
    int lane = tid & 63, w = tid >> 6;
    int quad = lane >> 4, cl = lane & 15;
    int qt = (TSEQ / 64 - 1) - blockIdx.x;   // reversed: big blocks first
    int bh = blockIdx.y;                     // b*8 + hd
    int b = bh >> 3, hd = bh & 7;
    int q0 = qt * 64;
    const short* Qb = q3;
    const short* Kb = q3 + Q3_K_OFF + (size_t)b * 2048 * 512 + hd * 64;
    const short* Vb = q3 + Q3_VT_OFF + (size_t)bh * 64 * 2048;
    short* Pw = &Ps[w][0];

    short8 qf[2];
    {
        const short* qrow = Qb + (size_t)(b * 2048 + q0 + w * 16 + cl) * 512 + hd * 64;
        qf[0] = *(const short8*)(qrow + quad * 8);
        qf[1] = *(const short8*)(qrow + 32 + quad * 8);
    }

    float l_r[4] = {0.f, 0.f, 0.f, 0.f};
    f32x4 o_acc[4] = {};

    int nkt = (q0 + 64 + 127) >> 7;

    for (int kt = 0; kt < nkt; kt++) {
        int k0 = kt * 128;

        // ---- S strip = Q·K^T (16 x 128); K fragments straight from global/L2 ----
        f32x4 s[8];
        #pragma unroll
        for (int j = 0; j < 8; j++) {
            const short* krow = Kb + (size_t)(k0 + j * 16 + cl) * 512;
            short8 kf0 = *(const short8*)(krow + quad * 8);
            short8 kf1 = *(const short8*)(krow + 32 + quad * 8);
            f32x4 a = {};
            a = __builtin_amdgcn_mfma_f32_16x16x32_bf16(qf[0], kf0, a, 0, 0, 0);
            a = __builtin_amdgcn_mfma_f32_16x16x32_bf16(qf[1], kf1, a, 0, 0, 0);
            s[j] = a;
        }

        // ---- scale + mask + exp (fixed-m: scores are O(1)) ----
        int grow = q0 + w * 16 + quad * 4;
        bool last = (kt == nkt - 1);
        #pragma unroll
        for (int j = 0; j < 8; j++)
            #pragma unroll
            for (int r = 0; r < 4; r++) {
                bool masked = last && (k0 + j * 16 + cl) > (grow + r);
                float p = masked ? 0.f : __expf(s[j][r] * 0.125f);
                s[j][r] = p;
                l_r[r] += p;
            }

        // ---- P (C layout) -> wave-local LDS -> A layout (no barrier needed) ----
        #pragma unroll
        for (int j = 0; j < 8; j++) {
            int key = j * 16 + cl;
            #pragma unroll
            for (int r = 0; r < 4; r++)
                Pw[pswz(quad * 4 + r, key)] = f2bs(s[j][r]);
        }
        short8 pf[4];
        #pragma unroll
        for (int c = 0; c < 4; c++)
            pf[c] = *(short8*)&Pw[pswz(cl, c * 32 + quad * 8)];

        // ---- O += P·V; Vt fragments straight from global/L2 ----
        #pragma unroll
        for (int j = 0; j < 4; j++) {
            const short* vrow = Vb + (size_t)(j * 16 + cl) * 2048 + k0;
            #pragma unroll
            for (int c = 0; c < 4; c++) {
                short8 vf = *(const short8*)(vrow + c * 32 + quad * 8);
                o_acc[j] = __builtin_amdgcn_mfma_f32_16x16x32_bf16(
                    pf[c], vf, o_acc[j], 0, 0, 0);
            }
        }
    }

    // ---- epilogue: one l-reduction per row, then O/l ----
    int grow = q0 + w * 16 + quad * 4;
    #pragma unroll
    for (int r = 0; r < 4; r++) {
        float l = l_r[r];
        #pragma unroll
        for (int m = 1; m < 16; m <<= 1) l += __shfl_xor(l, m, 64);
        float inv = 1.f / l;
        #pragma unroll
        for (int j = 0; j < 4; j++)
            out[(size_t)(b * TSEQ + grow + r) * DM + hd * DH + j * 16 + cl] =
                __float2bfloat16(o_acc[j][r] * inv);
    }
}

// ------------- host-side model driver, templated on weight dtype --------------------
template<typename WT>
static void run_model(const int* x, const float* tok, const float* pos,
    const WT* qkvw, const WT* projw,
    const float* ln1w, const float* ln1b, const float* ln2w, const float* ln2b,
    const WT* fc1w, const WT* fc2w, const float* lnfw, const float* lnfb,
    const WT* headw, float* h, bf16* xn, bf16* q3, float* dout, hipStream_t stream)
{
    emb_kernel<<<ROWS * DM / 256, 256, 0, stream>>>(x, tok, pos, h);

    for (int l = 0; l < DEPTH; l++) {
        ln_kernel<<<ROWS / 4, 256, 0, stream>>>(h, ln1w + l * DM, ln1b + l * DM, xn);
        mfma_gemm<4, WT><<<dim3(3 * DM / 128, ROWS / 128), 256, 0, stream>>>(
            xn, qkvw + (size_t)l * 3 * DM * DM, q3, ROWS, 3 * DM, DM);
        fattn_kernel<<<dim3(TSEQ / 64, BATCH * NH), 256, 0, stream>>>((short*)q3, xn);
        mfma_gemm_n64<1, WT><<<dim3(DM / 64, ROWS / 128), 256, 0, stream>>>(
            xn, projw + (size_t)l * DM * DM, h, ROWS, DM, DM, DM);
        ln_kernel<<<ROWS / 4, 256, 0, stream>>>(h, ln2w + l * DM, ln2b + l * DM, xn);
        for (int p = 0; p < 2; p++) {
            mfma_gemm<2, WT><<<dim3(1024 / 128, ROWS / 128), 256, 0, stream>>>(
                xn, fc1w + (size_t)l * DFF * DM + (size_t)p * 1024 * DM,
                q3, ROWS, 1024, DM);
            mfma_gemm_n64<1, WT><<<dim3(DM / 64, ROWS / 128), 256, 0, stream>>>(
                q3, fc2w + (size_t)l * DM * DFF + (size_t)p * 1024,
                h, ROWS, DM, 1024, DFF);
        }
    }

    ln_kernel<<<ROWS / 4, 256, 0, stream>>>(h, lnfw, lnfb, xn);
    mfma_gemm_n64<3, WT><<<dim3(NVOCAB / 64, ROWS / 128), 256, 0, stream>>>(
        xn, headw, dout, ROWS, NVOCAB, DM, DM);
}

extern "C" void kernel_launch(void* const* d_in, const int* in_sizes, int n_in,
                              void* d_out, int out_size, void* d_ws, size_t ws_size,
                              hipStream_t stream)
{
    const int*   x     = (const int*)d_in[0];
    const float* tok   = (const float*)d_in[1];
    const float* pos   = (const float*)d_in[2];
    const float* qkvw  = (const float*)d_in[3];
    const float* projw = (const float*)d_in[4];
    const float* ln1w  = (const float*)d_in[5];
    const float* ln1b  = (const float*)d_in[6];
    const float* ln2w  = (const float*)d_in[7];
    const float* ln2b  = (const float*)d_in[8];
    const float* fc1w  = (const float*)d_in[9];
    const float* fc2w  = (const float*)d_in[10];
    const float* lnfw  = (const float*)d_in[11];
    const float* lnfb  = (const float*)d_in[12];
    const float* headw = (const float*)d_in[13];

    // ws: h fp32 [4096,512] @0 (8 MiB) | xn bf16 @8MiB (4 MiB) | q3 @12MiB (12 MiB)
    // | bf16 weights @24MiB (36.3 MiB) when ws_size permits.
    char* ws = (char*)d_ws;
    float* h  = (float*)ws;
    bf16*  xn = (bf16*)(ws + (8u << 20));
    bf16*  q3 = (bf16*)(ws + (12u << 20));

    const size_t need = ((size_t)24 << 20) + 2 * SZ_ALL;

    if (ws_size >= need) {
        bf16* wb = (bf16*)(ws + (24u << 20));
        w2b_all<<<SZ_ALL / 2048, 256, 0, stream>>>(qkvw, projw, fc1w, fc2w, headw, wb);
        const bf16* qkvwb  = wb;
        const bf16* projwb = qkvwb + SZ_QKV;
        const bf16* fc1wb  = projwb + SZ_PROJ;
        const bf16* fc2wb  = fc1wb + SZ_FC1;
        const bf16* headwb = fc2wb + SZ_FC2;
        run_model<bf16>(x, tok, pos, qkvwb, projwb, ln1w, ln1b, ln2w, ln2b,
                        fc1wb, fc2wb, lnfw, lnfb, headwb,
                        h, xn, q3, (float*)d_out, stream);
    } else {
        run_model<float>(x, tok, pos, qkvw, projw, ln1w, ln1b, ln2w, ln2b,
                         fc1w, fc2w, lnfw, lnfb, headw,
                         h, xn, q3, (float*)d_out, stream);
    }
}

// Round 12
// 1298.024 us; speedup vs baseline: 1.3936x; 1.3936x over previous
//
#include <hip/hip_runtime.h>
#include <hip/hip_bf16.h>
#include <math.h>

typedef __hip_bfloat16 bf16;
typedef __attribute__((ext_vector_type(8))) short short8;
typedef __attribute__((ext_vector_type(4))) float f32x4;

#define DEPTH 6
#define DM    512
#define NH    8
#define DH    64
#define DFF   2048
#define TSEQ  2048
#define BATCH 2
#define ROWS  (BATCH*TSEQ)   // 4096
#define NVOCAB 256

// q3 region layout (elements): Q [4096*512] | K [4096*512] | Vt [16][64][2048]
#define Q3_K_OFF  2097152
#define Q3_VT_OFF 4194304

constexpr size_t SZ_QKV  = (size_t)DEPTH * 3 * DM * DM;   // 4718592
constexpr size_t SZ_PROJ = (size_t)DEPTH * DM * DM;       // 1572864
constexpr size_t SZ_FC1  = (size_t)DEPTH * DFF * DM;      // 6291456
constexpr size_t SZ_FC2  = SZ_FC1;
constexpr size_t SZ_HEAD = (size_t)NVOCAB * DM;           // 131072
constexpr size_t SZ_ALL  = SZ_QKV + SZ_PROJ + SZ_FC1 + SZ_FC2 + SZ_HEAD;

// async global->LDS, 16 B per lane; LDS dest must be wave-uniform base + lane*16
#define GLDS(gp, lp) __builtin_amdgcn_global_load_lds( \
    (const __attribute__((address_space(1))) void*)(gp), \
    (__attribute__((address_space(3))) void*)(lp), 16, 0, 0)

__device__ __forceinline__ short f2bs(float x) {
    union { bf16 b; short s; } u; u.b = __float2bfloat16(x); return u.s;
}

// ------------- all weights fp32 -> bf16 (single dispatch, contiguous dst) -----------
__global__ __launch_bounds__(256) void w2b_all(const float* __restrict__ q,
    const float* __restrict__ p, const float* __restrict__ f1,
    const float* __restrict__ f2, const float* __restrict__ hw, bf16* __restrict__ dst)
{
    size_t i = ((size_t)blockIdx.x * 256 + threadIdx.x) * 8;
    const float* s; size_t off;
    if      (i < SZ_QKV)                               { s = q;  off = 0; }
    else if (i < SZ_QKV + SZ_PROJ)                     { s = p;  off = SZ_QKV; }
    else if (i < SZ_QKV + SZ_PROJ + SZ_FC1)            { s = f1; off = SZ_QKV + SZ_PROJ; }
    else if (i < SZ_QKV + SZ_PROJ + SZ_FC1 + SZ_FC2)   { s = f2; off = SZ_QKV + SZ_PROJ + SZ_FC1; }
    else                                               { s = hw; off = SZ_QKV + SZ_PROJ + SZ_FC1 + SZ_FC2; }
    float4 f0 = *(const float4*)(s + (i - off));
    float4 f1v = *(const float4*)(s + (i - off) + 4);
    short8 o;
    o[0] = f2bs(f0.x); o[1] = f2bs(f0.y); o[2] = f2bs(f0.z); o[3] = f2bs(f0.w);
    o[4] = f2bs(f1v.x); o[5] = f2bs(f1v.y); o[6] = f2bs(f1v.z); o[7] = f2bs(f1v.w);
    *(short8*)((short*)dst + i) = o;
}

// ------------- embedding ------------------------------------------------------------
__global__ __launch_bounds__(256) void emb_kernel(const int* __restrict__ x,
    const float* __restrict__ tok, const float* __restrict__ pos, float* __restrict__ h)
{
    int i = blockIdx.x * 256 + threadIdx.x;
    int d = i & (DM - 1);
    int r = i >> 9;
    int t = r & (TSEQ - 1);
    h[i] = tok[x[r] * DM + d] + pos[t * DM + d];
}

// ------------- layernorm: wave per row, fp32 in, bf16 out ---------------------------
__global__ __launch_bounds__(256) void ln_kernel(const float* __restrict__ x,
    const float* __restrict__ w, const float* __restrict__ b, bf16* __restrict__ out)
{
    int row = blockIdx.x * 4 + (threadIdx.x >> 6);
    int lane = threadIdx.x & 63;
    const float* xr = x + (size_t)row * DM;

    float4 v0 = *(const float4*)(xr + lane * 4);
    float4 v1 = *(const float4*)(xr + 256 + lane * 4);

    float s = v0.x + v0.y + v0.z + v0.w + v1.x + v1.y + v1.z + v1.w;
    #pragma unroll
    for (int m = 1; m < 64; m <<= 1) s += __shfl_xor(s, m, 64);
    float mu = s * (1.f / DM);

    float var = (v0.x-mu)*(v0.x-mu) + (v0.y-mu)*(v0.y-mu) + (v0.z-mu)*(v0.z-mu)
              + (v0.w-mu)*(v0.w-mu) + (v1.x-mu)*(v1.x-mu) + (v1.y-mu)*(v1.y-mu)
              + (v1.z-mu)*(v1.z-mu) + (v1.w-mu)*(v1.w-mu);
    #pragma unroll
    for (int m = 1; m < 64; m <<= 1) var += __shfl_xor(var, m, 64);
    float rstd = rsqrtf(var * (1.f / DM) + 1e-5f);

    float4 w0 = *(const float4*)(w + lane * 4);
    float4 w1 = *(const float4*)(w + 256 + lane * 4);
    float4 b0 = *(const float4*)(b + lane * 4);
    float4 b1 = *(const float4*)(b + 256 + lane * 4);

    short4 o0, o1;
    o0.x = f2bs((v0.x - mu) * rstd * w0.x + b0.x);
    o0.y = f2bs((v0.y - mu) * rstd * w0.y + b0.y);
    o0.z = f2bs((v0.z - mu) * rstd * w0.z + b0.z);
    o0.w = f2bs((v0.w - mu) * rstd * w0.w + b0.w);
    o1.x = f2bs((v1.x - mu) * rstd * w1.x + b1.x);
    o1.y = f2bs((v1.y - mu) * rstd * w1.y + b1.y);
    o1.z = f2bs((v1.z - mu) * rstd * w1.z + b1.z);
    o1.w = f2bs((v1.w - mu) * rstd * w1.w + b1.w);
    *(short4*)(out + (size_t)row * DM + lane * 4) = o0;
    *(short4*)(out + (size_t)row * DM + 256 + lane * 4) = o1;
}

// ------------- MFMA GEMM 128x128: C = A(bf16) * W^T; WT = bf16 (GLDS) or fp32 -------
// EPI: 0 bf16 store, 1 fp32 +=, 2 GELU->bf16, 3 f32 store, 4 qkv split (Q|K|Vt)
template<int EPI, typename WT>
__global__ __launch_bounds__(256) void mfma_gemm(const bf16* __restrict__ A,
    const WT* __restrict__ W, void* __restrict__ Cv, int M, int N, int K)
{
    __shared__ short As[128 * 32];
    __shared__ short Bs[128 * 32];
    int tid = threadIdx.x;
    int bm0 = blockIdx.y * 128, bn0 = blockIdx.x * 128;
    int lane = tid & 63, w = tid >> 6;
    int wr = (w >> 1) * 64, wc = (w & 1) * 64;
    int fr = lane & 15, fk = (lane >> 4) * 8;

    f32x4 acc[4][4] = {};

    for (int k0 = 0; k0 < K; k0 += 32) {
        #pragma unroll
        for (int it = 0; it < 2; it++) {
            int c = it * 256 + tid;
            int row = c >> 2, kc = (c & 3) * 8;
            GLDS((const short*)A + (size_t)(bm0 + row) * K + k0 + kc, &As[c * 8]);
        }
        if constexpr (sizeof(WT) == 2) {
            #pragma unroll
            for (int it = 0; it < 2; it++) {
                int c = it * 256 + tid;
                int row = c >> 2, kc = (c & 3) * 8;
                GLDS((const short*)W + (size_t)(bn0 + row) * K + k0 + kc, &Bs[c * 8]);
            }
        } else {
            #pragma unroll
            for (int it = 0; it < 2; it++) {
                int c = it * 256 + tid;
                int row = c >> 2, kc = (c & 3) * 8;
                const float* wp = (const float*)W + (size_t)(bn0 + row) * K + k0 + kc;
                float4 f0 = *(const float4*)wp;
                float4 f1 = *(const float4*)(wp + 4);
                short8 p;
                p[0] = f2bs(f0.x); p[1] = f2bs(f0.y); p[2] = f2bs(f0.z); p[3] = f2bs(f0.w);
                p[4] = f2bs(f1.x); p[5] = f2bs(f1.y); p[6] = f2bs(f1.z); p[7] = f2bs(f1.w);
                *(short8*)&Bs[c * 8] = p;
            }
        }
        __syncthreads();

        short8 af[4], bfr[4];
        #pragma unroll
        for (int i = 0; i < 4; i++)
            af[i] = *(short8*)&As[(wr + i * 16 + fr) * 32 + fk];
        #pragma unroll
        for (int j = 0; j < 4; j++)
            bfr[j] = *(short8*)&Bs[(wc + j * 16 + fr) * 32 + fk];
        #pragma unroll
        for (int i = 0; i < 4; i++)
            #pragma unroll
            for (int j = 0; j < 4; j++)
                acc[i][j] = __builtin_amdgcn_mfma_f32_16x16x32_bf16(
                    af[i], bfr[j], acc[i][j], 0, 0, 0);
        __syncthreads();
    }

    int cr = (lane >> 4) * 4, cc = lane & 15;
    #pragma unroll
    for (int i = 0; i < 4; i++)
        #pragma unroll
        for (int j = 0; j < 4; j++)
            #pragma unroll
            for (int r = 0; r < 4; r++) {
                int m = bm0 + wr + i * 16 + cr + r;
                int n = bn0 + wc + j * 16 + cc;
                float v = acc[i][j][r];
                if (EPI == 4) {
                    // qkv split: Q | K row-major (stride 512), V transposed per head
                    short* q3s = (short*)Cv;
                    short sv = f2bs(v);
                    if (n < 512)
                        q3s[(size_t)m * 512 + n] = sv;
                    else if (n < 1024)
                        q3s[Q3_K_OFF + (size_t)m * 512 + (n - 512)] = sv;
                    else {
                        int bb = m >> 11, key = m & 2047;
                        int hd = (n - 1024) >> 6, dim = (n - 1024) & 63;
                        q3s[Q3_VT_OFF + (((size_t)(bb * 8 + hd) * 64 + dim) << 11) + key] = sv;
                    }
                } else {
                    size_t o = (size_t)m * N + n;
                    if (EPI == 0)      ((bf16*)Cv)[o] = __float2bfloat16(v);
                    else if (EPI == 1) ((float*)Cv)[o] += v;
                    else if (EPI == 2) ((bf16*)Cv)[o] =
                        __float2bfloat16(0.5f * v * (1.0f + erff(v * 0.70710678118654752f)));
                    else               ((float*)Cv)[o] = v;
                }
            }
}

// ------------- MFMA GEMM 128x64 (narrow N: proj/fc2/head), B row stride ldb ---------
template<int EPI, typename WT>
__global__ __launch_bounds__(256) void mfma_gemm_n64(const bf16* __restrict__ A,
    const WT* __restrict__ W, void* __restrict__ Cv, int M, int N, int K, int ldb)
{
    __shared__ short As[128 * 32];
    __shared__ short Bs[64 * 32];
    int tid = threadIdx.x;
    int bm0 = blockIdx.y * 128, bn0 = blockIdx.x * 64;
    int lane = tid & 63, w = tid >> 6;
    int wm = (w & 1) * 64, wn = (w >> 1) * 32;
    int fr = lane & 15, fk = (lane >> 4) * 8;

    f32x4 acc[4][2] = {};

    for (int k0 = 0; k0 < K; k0 += 32) {
        #pragma unroll
        for (int it = 0; it < 2; it++) {
            int c = it * 256 + tid;
            int row = c >> 2, kc = (c & 3) * 8;
            GLDS((const short*)A + (size_t)(bm0 + row) * K + k0 + kc, &As[c * 8]);
        }
        if constexpr (sizeof(WT) == 2) {
            int row = tid >> 2, kc = (tid & 3) * 8;
            GLDS((const short*)W + (size_t)(bn0 + row) * ldb + k0 + kc, &Bs[tid * 8]);
        } else {
            int row = tid >> 2, kc = (tid & 3) * 8;
            const float* wp = (const float*)W + (size_t)(bn0 + row) * ldb + k0 + kc;
            float4 f0 = *(const float4*)wp;
            float4 f1 = *(const float4*)(wp + 4);
            short8 p;
            p[0] = f2bs(f0.x); p[1] = f2bs(f0.y); p[2] = f2bs(f0.z); p[3] = f2bs(f0.w);
            p[4] = f2bs(f1.x); p[5] = f2bs(f1.y); p[6] = f2bs(f1.z); p[7] = f2bs(f1.w);
            *(short8*)&Bs[tid * 8] = p;
        }
        __syncthreads();

        short8 af[4], bfr[2];
        #pragma unroll
        for (int i = 0; i < 4; i++)
            af[i] = *(short8*)&As[(wm + i * 16 + fr) * 32 + fk];
        #pragma unroll
        for (int j = 0; j < 2; j++)
            bfr[j] = *(short8*)&Bs[(wn + j * 16 + fr) * 32 + fk];
        #pragma unroll
        for (int i = 0; i < 4; i++)
            #pragma unroll
            for (int j = 0; j < 2; j++)
                acc[i][j] = __builtin_amdgcn_mfma_f32_16x16x32_bf16(
                    af[i], bfr[j], acc[i][j], 0, 0, 0);
        __syncthreads();
    }

    int cr = (lane >> 4) * 4, cc = lane & 15;
    #pragma unroll
    for (int i = 0; i < 4; i++)
        #pragma unroll
        for (int j = 0; j < 2; j++)
            #pragma unroll
            for (int r = 0; r < 4; r++) {
                int m = bm0 + wm + i * 16 + cr + r;
                int n = bn0 + wn + j * 16 + cc;
                size_t o = (size_t)m * N + n;
                float v = acc[i][j][r];
                if (EPI == 0)      ((bf16*)Cv)[o] = __float2bfloat16(v);
                else if (EPI == 1) ((float*)Cv)[o] += v;
                else if (EPI == 2) ((bf16*)Cv)[o] =
                    __float2bfloat16(0.5f * v * (1.0f + erff(v * 0.70710678118654752f)));
                else               ((float*)Cv)[o] = v;
            }
}

// ------------- MFMA flash attention v4: staged LDS, coalesced Vt, balanced qt -------
// Block = 64 queries (4 waves x 16-row strips), k-tile 128.
// qt = b ? bx : 31-bx: a CU's two blocks (by, by+8) pair big+small -> uniform 17 tiles.
// LDS: padded strides (72/136 shorts -> 2-way conflicts, free per m136).
__device__ __forceinline__ int pswz(int row, int col) {    // P strip: 16-chunk perm
    return row * 136 + ((((col >> 3) + row) & 15) << 3) + (col & 7);
}

__global__ __launch_bounds__(256) void fattn_kernel(const short* __restrict__ q3,
    bf16* __restrict__ out)
{
    __shared__ __align__(16) short Ks[128 * 72];     // [key][dim], pad 8
    __shared__ __align__(16) short Vt[64 * 136];     // [dim][key], pad 8
    __shared__ __align__(16) short Ps[4][16 * 136];  // per-wave P strip (pswz)

    int tid = threadIdx.x;
    int lane = tid & 63, w = tid >> 6;
    int quad = lane >> 4, cl = lane & 15;
    int bh = blockIdx.y;                     // b*8 + hd
    int b = bh >> 3, hd = bh & 7;
    int bx = blockIdx.x;                     // 0..31
    int qt = b ? bx : (31 - bx);             // balance across CU block pairs
    int q0 = qt * 64;
    const short* Qb = q3;
    const short* Kb = q3 + Q3_K_OFF + (size_t)b * 2048 * 512 + hd * 64;
    const short* Vb = q3 + Q3_VT_OFF + (size_t)bh * 64 * 2048;
    short* Pw = &Ps[w][0];

    short8 qf[2];
    {
        const short* qrow = Qb + (size_t)(b * 2048 + q0 + w * 16 + cl) * 512 + hd * 64;
        qf[0] = *(const short8*)(qrow + quad * 8);
        qf[1] = *(const short8*)(qrow + 32 + quad * 8);
    }

    float l_r[4] = {0.f, 0.f, 0.f, 0.f};
    f32x4 o_acc[4] = {};

    int nkt = (q0 + 64 + 127) >> 7;

    for (int kt = 0; kt < nkt; kt++) {
        int k0 = kt * 128;
        __syncthreads();   // previous tile fully consumed
        // ---- stage K [128][64]: 1024 chunks, coalesced loads, b128 writes ----
        #pragma unroll
        for (int it = 0; it < 2; it++) {
            int c = it * 512 + tid * 2;      // 2 consecutive chunks per thread
            int row = c >> 3, cc = c & 7;
            const short* src = Kb + (size_t)(k0 + row) * 512 + cc * 8;
            *(short8*)&Ks[row * 72 + cc * 8] = *(const short8*)src;
            *(short8*)&Ks[row * 72 + cc * 8 + 8] = *(const short8*)(src + 8);
        }
        // ---- stage Vt [64][128]: coalesced rows (keys contiguous) ----
        #pragma unroll
        for (int it = 0; it < 2; it++) {
            int c = it * 512 + tid * 2;
            int row = c >> 4, cc = c & 15;
            const short* src = Vb + (size_t)row * 2048 + k0 + cc * 8;
            *(short8*)&Vt[row * 136 + cc * 8] = *(const short8*)src;
            *(short8*)&Vt[row * 136 + cc * 8 + 8] = *(const short8*)(src + 8);
        }
        __syncthreads();

        // ---- S strip = Q·K^T (16 x 128) ----
        f32x4 s[8];
        #pragma unroll
        for (int j = 0; j < 8; j++) {
            int key = j * 16 + cl;
            short8 kf0 = *(short8*)&Ks[key * 72 + quad * 8];
            short8 kf1 = *(short8*)&Ks[key * 72 + 32 + quad * 8];
            f32x4 a = {};
            a = __builtin_amdgcn_mfma_f32_16x16x32_bf16(qf[0], kf0, a, 0, 0, 0);
            a = __builtin_amdgcn_mfma_f32_16x16x32_bf16(qf[1], kf1, a, 0, 0, 0);
            s[j] = a;
        }

        // ---- scale + mask + exp (fixed-m: scores are O(1)) ----
        int grow = q0 + w * 16 + quad * 4;
        bool last = (kt == nkt - 1);
        #pragma unroll
        for (int j = 0; j < 8; j++)
            #pragma unroll
            for (int r = 0; r < 4; r++) {
                bool masked = last && (k0 + j * 16 + cl) > (grow + r);
                float p = masked ? 0.f : __expf(s[j][r] * 0.125f);
                s[j][r] = p;
                l_r[r] += p;
            }

        // ---- P (C layout) -> wave-local LDS -> A layout (no barrier: wave-local) ----
        #pragma unroll
        for (int j = 0; j < 8; j++) {
            int key = j * 16 + cl;
            #pragma unroll
            for (int r = 0; r < 4; r++)
                Pw[pswz(quad * 4 + r, key)] = f2bs(s[j][r]);
        }
        short8 pf[4];
        #pragma unroll
        for (int c = 0; c < 4; c++)
            pf[c] = *(short8*)&Pw[pswz(cl, c * 32 + quad * 8)];

        // ---- O += P·V ----
        #pragma unroll
        for (int j = 0; j < 4; j++) {
            int dim = j * 16 + cl;
            #pragma unroll
            for (int c = 0; c < 4; c++) {
                short8 vf = *(short8*)&Vt[dim * 136 + c * 32 + quad * 8];
                o_acc[j] = __builtin_amdgcn_mfma_f32_16x16x32_bf16(
                    pf[c], vf, o_acc[j], 0, 0, 0);
            }
        }
    }

    // ---- epilogue: one l-reduction per row, then O/l ----
    int grow = q0 + w * 16 + quad * 4;
    #pragma unroll
    for (int r = 0; r < 4; r++) {
        float l = l_r[r];
        #pragma unroll
        for (int m = 1; m < 16; m <<= 1) l += __shfl_xor(l, m, 64);
        float inv = 1.f / l;
        #pragma unroll
        for (int j = 0; j < 4; j++)
            out[(size_t)(b * TSEQ + grow + r) * DM + hd * DH + j * 16 + cl] =
                __float2bfloat16(o_acc[j][r] * inv);
    }
}

// ------------- host-side model driver, templated on weight dtype --------------------
template<typename WT>
static void run_model(const int* x, const float* tok, const float* pos,
    const WT* qkvw, const WT* projw,
    const float* ln1w, const float* ln1b, const float* ln2w, const float* ln2b,
    const WT* fc1w, const WT* fc2w, const float* lnfw, const float* lnfb,
    const WT* headw, float* h, bf16* xn, bf16* q3, float* dout, hipStream_t stream)
{
    emb_kernel<<<ROWS * DM / 256, 256, 0, stream>>>(x, tok, pos, h);

    for (int l = 0; l < DEPTH; l++) {
        ln_kernel<<<ROWS / 4, 256, 0, stream>>>(h, ln1w + l * DM, ln1b + l * DM, xn);
        mfma_gemm<4, WT><<<dim3(3 * DM / 128, ROWS / 128), 256, 0, stream>>>(
            xn, qkvw + (size_t)l * 3 * DM * DM, q3, ROWS, 3 * DM, DM);
        fattn_kernel<<<dim3(TSEQ / 64, BATCH * NH), 256, 0, stream>>>((short*)q3, xn);
        mfma_gemm_n64<1, WT><<<dim3(DM / 64, ROWS / 128), 256, 0, stream>>>(
            xn, projw + (size_t)l * DM * DM, h, ROWS, DM, DM, DM);
        ln_kernel<<<ROWS / 4, 256, 0, stream>>>(h, ln2w + l * DM, ln2b + l * DM, xn);
        for (int p = 0; p < 2; p++) {
            mfma_gemm<2, WT><<<dim3(1024 / 128, ROWS / 128), 256, 0, stream>>>(
                xn, fc1w + (size_t)l * DFF * DM + (size_t)p * 1024 * DM,
                q3, ROWS, 1024, DM);
            mfma_gemm_n64<1, WT><<<dim3(DM / 64, ROWS / 128), 256, 0, stream>>>(
                q3, fc2w + (size_t)l * DM * DFF + (size_t)p * 1024,
                h, ROWS, DM, 1024, DFF);
        }
    }

    ln_kernel<<<ROWS / 4, 256, 0, stream>>>(h, lnfw, lnfb, xn);
    mfma_gemm_n64<3, WT><<<dim3(NVOCAB / 64, ROWS / 128), 256, 0, stream>>>(
        xn, headw, dout, ROWS, NVOCAB, DM, DM);
}

extern "C" void kernel_launch(void* const* d_in, const int* in_sizes, int n_in,
                              void* d_out, int out_size, void* d_ws, size_t ws_size,
                              hipStream_t stream)
{
    const int*   x     = (const int*)d_in[0];
    const float* tok   = (const float*)d_in[1];
    const float* pos   = (const float*)d_in[2];
    const float* qkvw  = (const float*)d_in[3];
    const float* projw = (const float*)d_in[4];
    const float* ln1w  = (const float*)d_in[5];
    const float* ln1b  = (const float*)d_in[6];
    const float* ln2w  = (const float*)d_in[7];
    const float* ln2b  = (const float*)d_in[8];
    const float* fc1w  = (const float*)d_in[9];
    const float* fc2w  = (const float*)d_in[10];
    const float* lnfw  = (const float*)d_in[11];
    const float* lnfb  = (const float*)d_in[12];
    const float* headw = (const float*)d_in[13];

    // ws: h fp32 [4096,512] @0 (8 MiB) | xn bf16 @8MiB (4 MiB) | q3 @12MiB (12 MiB)
    // | bf16 weights @24MiB (36.3 MiB) when ws_size permits.
    char* ws = (char*)d_ws;
    float* h  = (float*)ws;
    bf16*  xn = (bf16*)(ws + (8u << 20));
    bf16*  q3 = (bf16*)(ws + (12u << 20));

    const size_t need = ((size_t)24 << 20) + 2 * SZ_ALL;

    if (ws_size >= need) {
        bf16* wb = (bf16*)(ws + (24u << 20));
        w2b_all<<<SZ_ALL / 2048, 256, 0, stream>>>(qkvw, projw, fc1w, fc2w, headw, wb);
        const bf16* qkvwb  = wb;
        const bf16* projwb = qkvwb + SZ_QKV;
        const bf16* fc1wb  = projwb + SZ_PROJ;
        const bf16* fc2wb  = fc1wb + SZ_FC1;
        const bf16* headwb = fc2wb + SZ_FC2;
        run_model<bf16>(x, tok, pos, qkvwb, projwb, ln1w, ln1b, ln2w, ln2b,
                        fc1wb, fc2wb, lnfw, lnfb, headwb,
                        h, xn, q3, (float*)d_out, stream);
    } else {
        run_model<float>(x, tok, pos, qkvw, projw, ln1w, ln1b, ln2w, ln2b,
                         fc1w, fc2w, lnfw, lnfb, headw,
                         h, xn, q3, (float*)d_out, stream);
    }
}

// Round 13
// 1189.640 us; speedup vs baseline: 1.5206x; 1.0911x over previous
//
#include <hip/hip_runtime.h>
#include <hip/hip_bf16.h>
#include <math.h>

typedef __hip_bfloat16 bf16;
typedef __attribute__((ext_vector_type(8))) short short8;
typedef __attribute__((ext_vector_type(4))) float f32x4;

#define DEPTH 6
#define DM    512
#define NH    8
#define DH    64
#define DFF   2048
#define TSEQ  2048
#define BATCH 2
#define ROWS  (BATCH*TSEQ)   // 4096
#define NVOCAB 256

// q3 region layout (elements): Q [4096*512] | K [4096*512] | Vt [16][64][2048]
#define Q3_K_OFF  2097152
#define Q3_VT_OFF 4194304

constexpr size_t SZ_QKV  = (size_t)DEPTH * 3 * DM * DM;   // 4718592
constexpr size_t SZ_PROJ = (size_t)DEPTH * DM * DM;       // 1572864
constexpr size_t SZ_FC1  = (size_t)DEPTH * DFF * DM;      // 6291456
constexpr size_t SZ_FC2  = SZ_FC1;
constexpr size_t SZ_HEAD = (size_t)NVOCAB * DM;           // 131072
constexpr size_t SZ_ALL  = SZ_QKV + SZ_PROJ + SZ_FC1 + SZ_FC2 + SZ_HEAD;

// async global->LDS, 16 B per lane; LDS dest must be wave-uniform base + lane*16
#define GLDS(gp, lp) __builtin_amdgcn_global_load_lds( \
    (const __attribute__((address_space(1))) void*)(gp), \
    (__attribute__((address_space(3))) void*)(lp), 16, 0, 0)

__device__ __forceinline__ short f2bs(float x) {
    union { bf16 b; short s; } u; u.b = __float2bfloat16(x); return u.s;
}

// ------------- all weights fp32 -> bf16 (single dispatch, contiguous dst) -----------
__global__ __launch_bounds__(256) void w2b_all(const float* __restrict__ q,
    const float* __restrict__ p, const float* __restrict__ f1,
    const float* __restrict__ f2, const float* __restrict__ hw, bf16* __restrict__ dst)
{
    size_t i = ((size_t)blockIdx.x * 256 + threadIdx.x) * 8;
    const float* s; size_t off;
    if      (i < SZ_QKV)                               { s = q;  off = 0; }
    else if (i < SZ_QKV + SZ_PROJ)                     { s = p;  off = SZ_QKV; }
    else if (i < SZ_QKV + SZ_PROJ + SZ_FC1)            { s = f1; off = SZ_QKV + SZ_PROJ; }
    else if (i < SZ_QKV + SZ_PROJ + SZ_FC1 + SZ_FC2)   { s = f2; off = SZ_QKV + SZ_PROJ + SZ_FC1; }
    else                                               { s = hw; off = SZ_QKV + SZ_PROJ + SZ_FC1 + SZ_FC2; }
    float4 f0 = *(const float4*)(s + (i - off));
    float4 f1v = *(const float4*)(s + (i - off) + 4);
    short8 o;
    o[0] = f2bs(f0.x); o[1] = f2bs(f0.y); o[2] = f2bs(f0.z); o[3] = f2bs(f0.w);
    o[4] = f2bs(f1v.x); o[5] = f2bs(f1v.y); o[6] = f2bs(f1v.z); o[7] = f2bs(f1v.w);
    *(short8*)((short*)dst + i) = o;
}

// ------------- embedding ------------------------------------------------------------
__global__ __launch_bounds__(256) void emb_kernel(const int* __restrict__ x,
    const float* __restrict__ tok, const float* __restrict__ pos, float* __restrict__ h)
{
    int i = blockIdx.x * 256 + threadIdx.x;
    int d = i & (DM - 1);
    int r = i >> 9;
    int t = r & (TSEQ - 1);
    h[i] = tok[x[r] * DM + d] + pos[t * DM + d];
}

// ------------- layernorm: wave per row, fp32 in, bf16 out ---------------------------
__global__ __launch_bounds__(256) void ln_kernel(const float* __restrict__ x,
    const float* __restrict__ w, const float* __restrict__ b, bf16* __restrict__ out)
{
    int row = blockIdx.x * 4 + (threadIdx.x >> 6);
    int lane = threadIdx.x & 63;
    const float* xr = x + (size_t)row * DM;

    float4 v0 = *(const float4*)(xr + lane * 4);
    float4 v1 = *(const float4*)(xr + 256 + lane * 4);

    float s = v0.x + v0.y + v0.z + v0.w + v1.x + v1.y + v1.z + v1.w;
    #pragma unroll
    for (int m = 1; m < 64; m <<= 1) s += __shfl_xor(s, m, 64);
    float mu = s * (1.f / DM);

    float var = (v0.x-mu)*(v0.x-mu) + (v0.y-mu)*(v0.y-mu) + (v0.z-mu)*(v0.z-mu)
              + (v0.w-mu)*(v0.w-mu) + (v1.x-mu)*(v1.x-mu) + (v1.y-mu)*(v1.y-mu)
              + (v1.z-mu)*(v1.z-mu) + (v1.w-mu)*(v1.w-mu);
    #pragma unroll
    for (int m = 1; m < 64; m <<= 1) var += __shfl_xor(var, m, 64);
    float rstd = rsqrtf(var * (1.f / DM) + 1e-5f);

    float4 w0 = *(const float4*)(w + lane * 4);
    float4 w1 = *(const float4*)(w + 256 + lane * 4);
    float4 b0 = *(const float4*)(b + lane * 4);
    float4 b1 = *(const float4*)(b + 256 + lane * 4);

    short4 o0, o1;
    o0.x = f2bs((v0.x - mu) * rstd * w0.x + b0.x);
    o0.y = f2bs((v0.y - mu) * rstd * w0.y + b0.y);
    o0.z = f2bs((v0.z - mu) * rstd * w0.z + b0.z);
    o0.w = f2bs((v0.w - mu) * rstd * w0.w + b0.w);
    o1.x = f2bs((v1.x - mu) * rstd * w1.x + b1.x);
    o1.y = f2bs((v1.y - mu) * rstd * w1.y + b1.y);
    o1.z = f2bs((v1.z - mu) * rstd * w1.z + b1.z);
    o1.w = f2bs((v1.w - mu) * rstd * w1.w + b1.w);
    *(short4*)(out + (size_t)row * DM + lane * 4) = o0;
    *(short4*)(out + (size_t)row * DM + 256 + lane * 4) = o1;
}

// ------------- MFMA GEMM 128x128: C = A(bf16) * W^T; WT = bf16 (GLDS) or fp32 -------
// EPI: 0 bf16 store, 1 fp32 +=, 2 GELU->bf16, 3 f32 store, 4 qkv split (Q|K|Vt)
template<int EPI, typename WT>
__global__ __launch_bounds__(256) void mfma_gemm(const bf16* __restrict__ A,
    const WT* __restrict__ W, void* __restrict__ Cv, int M, int N, int K)
{
    __shared__ short As[128 * 32];
    __shared__ short Bs[128 * 32];
    int tid = threadIdx.x;
    int bm0 = blockIdx.y * 128, bn0 = blockIdx.x * 128;
    int lane = tid & 63, w = tid >> 6;
    int wr = (w >> 1) * 64, wc = (w & 1) * 64;
    int fr = lane & 15, fk = (lane >> 4) * 8;

    f32x4 acc[4][4] = {};

    for (int k0 = 0; k0 < K; k0 += 32) {
        #pragma unroll
        for (int it = 0; it < 2; it++) {
            int c = it * 256 + tid;
            int row = c >> 2, kc = (c & 3) * 8;
            GLDS((const short*)A + (size_t)(bm0 + row) * K + k0 + kc, &As[c * 8]);
        }
        if constexpr (sizeof(WT) == 2) {
            #pragma unroll
            for (int it = 0; it < 2; it++) {
                int c = it * 256 + tid;
                int row = c >> 2, kc = (c & 3) * 8;
                GLDS((const short*)W + (size_t)(bn0 + row) * K + k0 + kc, &Bs[c * 8]);
            }
        } else {
            #pragma unroll
            for (int it = 0; it < 2; it++) {
                int c = it * 256 + tid;
                int row = c >> 2, kc = (c & 3) * 8;
                const float* wp = (const float*)W + (size_t)(bn0 + row) * K + k0 + kc;
                float4 f0 = *(const float4*)wp;
                float4 f1 = *(const float4*)(wp + 4);
                short8 p;
                p[0] = f2bs(f0.x); p[1] = f2bs(f0.y); p[2] = f2bs(f0.z); p[3] = f2bs(f0.w);
                p[4] = f2bs(f1.x); p[5] = f2bs(f1.y); p[6] = f2bs(f1.z); p[7] = f2bs(f1.w);
                *(short8*)&Bs[c * 8] = p;
            }
        }
        __syncthreads();

        short8 af[4], bfr[4];
        #pragma unroll
        for (int i = 0; i < 4; i++)
            af[i] = *(short8*)&As[(wr + i * 16 + fr) * 32 + fk];
        #pragma unroll
        for (int j = 0; j < 4; j++)
            bfr[j] = *(short8*)&Bs[(wc + j * 16 + fr) * 32 + fk];
        #pragma unroll
        for (int i = 0; i < 4; i++)
            #pragma unroll
            for (int j = 0; j < 4; j++)
                acc[i][j] = __builtin_amdgcn_mfma_f32_16x16x32_bf16(
                    af[i], bfr[j], acc[i][j], 0, 0, 0);
        __syncthreads();
    }

    int cr = (lane >> 4) * 4, cc = lane & 15;
    #pragma unroll
    for (int i = 0; i < 4; i++)
        #pragma unroll
        for (int j = 0; j < 4; j++)
            #pragma unroll
            for (int r = 0; r < 4; r++) {
                int m = bm0 + wr + i * 16 + cr + r;
                int n = bn0 + wc + j * 16 + cc;
                float v = acc[i][j][r];
                if (EPI == 4) {
                    // qkv split: Q | K row-major (stride 512), V transposed per head
                    short* q3s = (short*)Cv;
                    short sv = f2bs(v);
                    if (n < 512)
                        q3s[(size_t)m * 512 + n] = sv;
                    else if (n < 1024)
                        q3s[Q3_K_OFF + (size_t)m * 512 + (n - 512)] = sv;
                    else {
                        int bb = m >> 11, key = m & 2047;
                        int hd = (n - 1024) >> 6, dim = (n - 1024) & 63;
                        q3s[Q3_VT_OFF + (((size_t)(bb * 8 + hd) * 64 + dim) << 11) + key] = sv;
                    }
                } else {
                    size_t o = (size_t)m * N + n;
                    if (EPI == 0)      ((bf16*)Cv)[o] = __float2bfloat16(v);
                    else if (EPI == 1) ((float*)Cv)[o] += v;
                    else if (EPI == 2) ((bf16*)Cv)[o] =
                        __float2bfloat16(0.5f * v * (1.0f + erff(v * 0.70710678118654752f)));
                    else               ((float*)Cv)[o] = v;
                }
            }
}

// ------------- MFMA GEMM 128x64 (narrow N: proj/fc2/head), B row stride ldb ---------
template<int EPI, typename WT>
__global__ __launch_bounds__(256) void mfma_gemm_n64(const bf16* __restrict__ A,
    const WT* __restrict__ W, void* __restrict__ Cv, int M, int N, int K, int ldb)
{
    __shared__ short As[128 * 32];
    __shared__ short Bs[64 * 32];
    int tid = threadIdx.x;
    int bm0 = blockIdx.y * 128, bn0 = blockIdx.x * 64;
    int lane = tid & 63, w = tid >> 6;
    int wm = (w & 1) * 64, wn = (w >> 1) * 32;
    int fr = lane & 15, fk = (lane >> 4) * 8;

    f32x4 acc[4][2] = {};

    for (int k0 = 0; k0 < K; k0 += 32) {
        #pragma unroll
        for (int it = 0; it < 2; it++) {
            int c = it * 256 + tid;
            int row = c >> 2, kc = (c & 3) * 8;
            GLDS((const short*)A + (size_t)(bm0 + row) * K + k0 + kc, &As[c * 8]);
        }
        if constexpr (sizeof(WT) == 2) {
            int row = tid >> 2, kc = (tid & 3) * 8;
            GLDS((const short*)W + (size_t)(bn0 + row) * ldb + k0 + kc, &Bs[tid * 8]);
        } else {
            int row = tid >> 2, kc = (tid & 3) * 8;
            const float* wp = (const float*)W + (size_t)(bn0 + row) * ldb + k0 + kc;
            float4 f0 = *(const float4*)wp;
            float4 f1 = *(const float4*)(wp + 4);
            short8 p;
            p[0] = f2bs(f0.x); p[1] = f2bs(f0.y); p[2] = f2bs(f0.z); p[3] = f2bs(f0.w);
            p[4] = f2bs(f1.x); p[5] = f2bs(f1.y); p[6] = f2bs(f1.z); p[7] = f2bs(f1.w);
            *(short8*)&Bs[tid * 8] = p;
        }
        __syncthreads();

        short8 af[4], bfr[2];
        #pragma unroll
        for (int i = 0; i < 4; i++)
            af[i] = *(short8*)&As[(wm + i * 16 + fr) * 32 + fk];
        #pragma unroll
        for (int j = 0; j < 2; j++)
            bfr[j] = *(short8*)&Bs[(wn + j * 16 + fr) * 32 + fk];
        #pragma unroll
        for (int i = 0; i < 4; i++)
            #pragma unroll
            for (int j = 0; j < 2; j++)
                acc[i][j] = __builtin_amdgcn_mfma_f32_16x16x32_bf16(
                    af[i], bfr[j], acc[i][j], 0, 0, 0);
        __syncthreads();
    }

    int cr = (lane >> 4) * 4, cc = lane & 15;
    #pragma unroll
    for (int i = 0; i < 4; i++)
        #pragma unroll
        for (int j = 0; j < 2; j++)
            #pragma unroll
            for (int r = 0; r < 4; r++) {
                int m = bm0 + wm + i * 16 + cr + r;
                int n = bn0 + wn + j * 16 + cc;
                size_t o = (size_t)m * N + n;
                float v = acc[i][j][r];
                if (EPI == 0)      ((bf16*)Cv)[o] = __float2bfloat16(v);
                else if (EPI == 1) ((float*)Cv)[o] += v;
                else if (EPI == 2) ((bf16*)Cv)[o] =
                    __float2bfloat16(0.5f * v * (1.0f + erff(v * 0.70710678118654752f)));
                else               ((float*)Cv)[o] = v;
            }
}

// ------------- MFMA flash attention v5: conflict-free staging, balanced qt ----------
// Same structure as r12 (50 us) but staging remapped: one wave writes 8 rows x 8
// chunks -> bank = 4*(row+cc) % 32, uniform coverage = zero write conflicts.
__device__ __forceinline__ int pswz(int row, int col) {    // P strip: 16-chunk perm
    return row * 136 + ((((col >> 3) + row) & 15) << 3) + (col & 7);
}

__global__ __launch_bounds__(256) void fattn_kernel(const short* __restrict__ q3,
    bf16* __restrict__ out)
{
    __shared__ __align__(16) short Ks[128 * 72];     // [key][dim], pad 8
    __shared__ __align__(16) short Vt[64 * 136];     // [dim][key], pad 8
    __shared__ __align__(16) short Ps[4][16 * 136];  // per-wave P strip (pswz)

    int tid = threadIdx.x;
    int lane = tid & 63, w = tid >> 6;
    int quad = lane >> 4, cl = lane & 15;
    int bh = blockIdx.y;                     // b*8 + hd
    int b = bh >> 3, hd = bh & 7;
    int bx = blockIdx.x;                     // 0..31
    int qt = b ? bx : (31 - bx);             // balance across CU block pairs
    int q0 = qt * 64;
    const short* Qb = q3;
    const short* Kb = q3 + Q3_K_OFF + (size_t)b * 2048 * 512 + hd * 64;
    const short* Vb = q3 + Q3_VT_OFF + (size_t)bh * 64 * 2048;
    short* Pw = &Ps[w][0];

    short8 qf[2];
    {
        const short* qrow = Qb + (size_t)(b * 2048 + q0 + w * 16 + cl) * 512 + hd * 64;
        qf[0] = *(const short8*)(qrow + quad * 8);
        qf[1] = *(const short8*)(qrow + 32 + quad * 8);
    }

    float l_r[4] = {0.f, 0.f, 0.f, 0.f};
    f32x4 o_acc[4] = {};

    int nkt = (q0 + 64 + 127) >> 7;
    int krow0 = tid >> 3, kcc = tid & 7;     // K staging: 32 rows x 8 chunks per it
    int vrow0 = tid >> 4, vcc = tid & 15;    // Vt staging: 16 rows x 16 chunks per it

    for (int kt = 0; kt < nkt; kt++) {
        int k0 = kt * 128;
        __syncthreads();   // previous tile fully consumed
        // ---- stage K [128][64]: wave covers 8 rows x 8 chunks -> conflict-free ----
        #pragma unroll
        for (int it = 0; it < 4; it++) {
            int row = it * 32 + krow0;
            *(short8*)&Ks[row * 72 + kcc * 8] =
                *(const short8*)(Kb + (size_t)(k0 + row) * 512 + kcc * 8);
        }
        // ---- stage Vt [64][128]: wave covers 4 rows x 16 chunks -> conflict-free ----
        #pragma unroll
        for (int it = 0; it < 4; it++) {
            int row = it * 16 + vrow0;
            *(short8*)&Vt[row * 136 + vcc * 8] =
                *(const short8*)(Vb + (size_t)row * 2048 + k0 + vcc * 8);
        }
        __syncthreads();

        // ---- S strip = Q·K^T (16 x 128) ----
        f32x4 s[8];
        #pragma unroll
        for (int j = 0; j < 8; j++) {
            int key = j * 16 + cl;
            short8 kf0 = *(short8*)&Ks[key * 72 + quad * 8];
            short8 kf1 = *(short8*)&Ks[key * 72 + 32 + quad * 8];
            f32x4 a = {};
            a = __builtin_amdgcn_mfma_f32_16x16x32_bf16(qf[0], kf0, a, 0, 0, 0);
            a = __builtin_amdgcn_mfma_f32_16x16x32_bf16(qf[1], kf1, a, 0, 0, 0);
            s[j] = a;
        }

        // ---- scale + mask + exp (fixed-m: scores are O(1)) ----
        int grow = q0 + w * 16 + quad * 4;
        bool last = (kt == nkt - 1);
        #pragma unroll
        for (int j = 0; j < 8; j++)
            #pragma unroll
            for (int r = 0; r < 4; r++) {
                bool masked = last && (k0 + j * 16 + cl) > (grow + r);
                float p = masked ? 0.f : __expf(s[j][r] * 0.125f);
                s[j][r] = p;
                l_r[r] += p;
            }

        // ---- P (C layout) -> wave-local LDS -> A layout (no barrier: wave-local) ----
        #pragma unroll
        for (int j = 0; j < 8; j++) {
            int key = j * 16 + cl;
            #pragma unroll
            for (int r = 0; r < 4; r++)
                Pw[pswz(quad * 4 + r, key)] = f2bs(s[j][r]);
        }
        short8 pf[4];
        #pragma unroll
        for (int c = 0; c < 4; c++)
            pf[c] = *(short8*)&Pw[pswz(cl, c * 32 + quad * 8)];

        // ---- O += P·V ----
        #pragma unroll
        for (int j = 0; j < 4; j++) {
            int dim = j * 16 + cl;
            #pragma unroll
            for (int c = 0; c < 4; c++) {
                short8 vf = *(short8*)&Vt[dim * 136 + c * 32 + quad * 8];
                o_acc[j] = __builtin_amdgcn_mfma_f32_16x16x32_bf16(
                    pf[c], vf, o_acc[j], 0, 0, 0);
            }
        }
    }

    // ---- epilogue: one l-reduction per row, then O/l ----
    int grow = q0 + w * 16 + quad * 4;
    #pragma unroll
    for (int r = 0; r < 4; r++) {
        float l = l_r[r];
        #pragma unroll
        for (int m = 1; m < 16; m <<= 1) l += __shfl_xor(l, m, 64);
        float inv = 1.f / l;
        #pragma unroll
        for (int j = 0; j < 4; j++)
            out[(size_t)(b * TSEQ + grow + r) * DM + hd * DH + j * 16 + cl] =
                __float2bfloat16(o_acc[j][r] * inv);
    }
}

// ------------- host-side model driver, templated on weight dtype --------------------
template<typename WT>
static void run_model(const int* x, const float* tok, const float* pos,
    const WT* qkvw, const WT* projw,
    const float* ln1w, const float* ln1b, const float* ln2w, const float* ln2b,
    const WT* fc1w, const WT* fc2w, const float* lnfw, const float* lnfb,
    const WT* headw, float* h, bf16* xn, bf16* q3, bf16* hid16,
    float* dout, hipStream_t stream)
{
    emb_kernel<<<ROWS * DM / 256, 256, 0, stream>>>(x, tok, pos, h);

    for (int l = 0; l < DEPTH; l++) {
        ln_kernel<<<ROWS / 4, 256, 0, stream>>>(h, ln1w + l * DM, ln1b + l * DM, xn);
        mfma_gemm<4, WT><<<dim3(3 * DM / 128, ROWS / 128), 256, 0, stream>>>(
            xn, qkvw + (size_t)l * 3 * DM * DM, q3, ROWS, 3 * DM, DM);
        fattn_kernel<<<dim3(TSEQ / 64, BATCH * NH), 256, 0, stream>>>((short*)q3, xn);
        mfma_gemm_n64<1, WT><<<dim3(DM / 64, ROWS / 128), 256, 0, stream>>>(
            xn, projw + (size_t)l * DM * DM, h, ROWS, DM, DM, DM);
        ln_kernel<<<ROWS / 4, 256, 0, stream>>>(h, ln2w + l * DM, ln2b + l * DM, xn);
        if (hid16) {
            // fused MLP: fc1 full N=2048 (grid 512 = 2 blocks/CU), fc2 single K=2048
            mfma_gemm<2, WT><<<dim3(DFF / 128, ROWS / 128), 256, 0, stream>>>(
                xn, fc1w + (size_t)l * DFF * DM, hid16, ROWS, DFF, DM);
            mfma_gemm_n64<1, WT><<<dim3(DM / 64, ROWS / 128), 256, 0, stream>>>(
                hid16, fc2w + (size_t)l * DM * DFF, h, ROWS, DM, DFF, DFF);
        } else {
            for (int p = 0; p < 2; p++) {
                mfma_gemm<2, WT><<<dim3(1024 / 128, ROWS / 128), 256, 0, stream>>>(
                    xn, fc1w + (size_t)l * DFF * DM + (size_t)p * 1024 * DM,
                    q3, ROWS, 1024, DM);
                mfma_gemm_n64<1, WT><<<dim3(DM / 64, ROWS / 128), 256, 0, stream>>>(
                    q3, fc2w + (size_t)l * DM * DFF + (size_t)p * 1024,
                    h, ROWS, DM, 1024, DFF);
            }
        }
    }

    ln_kernel<<<ROWS / 4, 256, 0, stream>>>(h, lnfw, lnfb, xn);
    mfma_gemm_n64<3, WT><<<dim3(NVOCAB / 64, ROWS / 128), 256, 0, stream>>>(
        xn, headw, dout, ROWS, NVOCAB, DM, DM);
}

extern "C" void kernel_launch(void* const* d_in, const int* in_sizes, int n_in,
                              void* d_out, int out_size, void* d_ws, size_t ws_size,
                              hipStream_t stream)
{
    const int*   x     = (const int*)d_in[0];
    const float* tok   = (const float*)d_in[1];
    const float* pos   = (const float*)d_in[2];
    const float* qkvw  = (const float*)d_in[3];
    const float* projw = (const float*)d_in[4];
    const float* ln1w  = (const float*)d_in[5];
    const float* ln1b  = (const float*)d_in[6];
    const float* ln2w  = (const float*)d_in[7];
    const float* ln2b  = (const float*)d_in[8];
    const float* fc1w  = (const float*)d_in[9];
    const float* fc2w  = (const float*)d_in[10];
    const float* lnfw  = (const float*)d_in[11];
    const float* lnfb  = (const float*)d_in[12];
    const float* headw = (const float*)d_in[13];

    // ws: h fp32 @0 (8 MiB) | xn bf16 @8MiB (4 MiB) | q3 @12MiB (12 MiB)
    // | bf16 weights @24MiB (~36.3 MiB) | hidden16 bf16 [4096,2048] (16 MiB) if room.
    char* ws = (char*)d_ws;
    float* h  = (float*)ws;
    bf16*  xn = (bf16*)(ws + (8u << 20));
    bf16*  q3 = (bf16*)(ws + (12u << 20));

    const size_t wb_off = (size_t)24 << 20;
    const size_t hid_off = wb_off + 2 * SZ_ALL;
    const size_t need1 = hid_off;                       // bf16 weights, split MLP
    const size_t need2 = hid_off + ((size_t)16 << 20);  // + fused MLP hidden

    if (ws_size >= need1) {
        bf16* wb = (bf16*)(ws + wb_off);
        bf16* hid16 = (ws_size >= need2) ? (bf16*)(ws + hid_off) : (bf16*)nullptr;
        w2b_all<<<SZ_ALL / 2048, 256, 0, stream>>>(qkvw, projw, fc1w, fc2w, headw, wb);
        const bf16* qkvwb  = wb;
        const bf16* projwb = qkvwb + SZ_QKV;
        const bf16* fc1wb  = projwb + SZ_PROJ;
        const bf16* fc2wb  = fc1wb + SZ_FC1;
        const bf16* headwb = fc2wb + SZ_FC2;
        run_model<bf16>(x, tok, pos, qkvwb, projwb, ln1w, ln1b, ln2w, ln2b,
                        fc1wb, fc2wb, lnfw, lnfb, headwb,
                        h, xn, q3, hid16, (float*)d_out, stream);
    } else {
        run_model<float>(x, tok, pos, qkvw, projw, ln1w, ln1b, ln2w, ln2b,
                         fc1w, fc2w, lnfw, lnfb, headw,
                         h, xn, q3, (bf16*)nullptr, (float*)d_out, stream);
    }
}

// Round 14
// 1095.671 us; speedup vs baseline: 1.6510x; 1.0858x over previous
//
#include <hip/hip_runtime.h>
#include <hip/hip_bf16.h>
#include <math.h>

typedef __hip_bfloat16 bf16;
typedef __attribute__((ext_vector_type(8))) short short8;
typedef __attribute__((ext_vector_type(4))) float f32x4;

#define DEPTH 6
#define DM    512
#define NH    8
#define DH    64
#define DFF   2048
#define TSEQ  2048
#define BATCH 2
#define ROWS  (BATCH*TSEQ)   // 4096
#define NVOCAB 256

// q3 region layout (elements): Q [4096*512] | K [4096*512] | Vt [16][64][2048]
#define Q3_K_OFF  2097152
#define Q3_VT_OFF 4194304

constexpr size_t SZ_QKV  = (size_t)DEPTH * 3 * DM * DM;   // 4718592
constexpr size_t SZ_PROJ = (size_t)DEPTH * DM * DM;       // 1572864
constexpr size_t SZ_FC1  = (size_t)DEPTH * DFF * DM;      // 6291456
constexpr size_t SZ_FC2  = SZ_FC1;
constexpr size_t SZ_HEAD = (size_t)NVOCAB * DM;           // 131072
constexpr size_t SZ_ALL  = SZ_QKV + SZ_PROJ + SZ_FC1 + SZ_FC2 + SZ_HEAD;

// async global->LDS, 16 B per lane; LDS dest must be wave-uniform base + lane*16
#define GLDS(gp, lp) __builtin_amdgcn_global_load_lds( \
    (const __attribute__((address_space(1))) void*)(gp), \
    (__attribute__((address_space(3))) void*)(lp), 16, 0, 0)

__device__ __forceinline__ short f2bs(float x) {
    union { bf16 b; short s; } u; u.b = __float2bfloat16(x); return u.s;
}

// ------------- all weights fp32 -> bf16 (single dispatch, contiguous dst) -----------
__global__ __launch_bounds__(256) void w2b_all(const float* __restrict__ q,
    const float* __restrict__ p, const float* __restrict__ f1,
    const float* __restrict__ f2, const float* __restrict__ hw, bf16* __restrict__ dst)
{
    size_t i = ((size_t)blockIdx.x * 256 + threadIdx.x) * 8;
    const float* s; size_t off;
    if      (i < SZ_QKV)                               { s = q;  off = 0; }
    else if (i < SZ_QKV + SZ_PROJ)                     { s = p;  off = SZ_QKV; }
    else if (i < SZ_QKV + SZ_PROJ + SZ_FC1)            { s = f1; off = SZ_QKV + SZ_PROJ; }
    else if (i < SZ_QKV + SZ_PROJ + SZ_FC1 + SZ_FC2)   { s = f2; off = SZ_QKV + SZ_PROJ + SZ_FC1; }
    else                                               { s = hw; off = SZ_QKV + SZ_PROJ + SZ_FC1 + SZ_FC2; }
    float4 f0 = *(const float4*)(s + (i - off));
    float4 f1v = *(const float4*)(s + (i - off) + 4);
    short8 o;
    o[0] = f2bs(f0.x); o[1] = f2bs(f0.y); o[2] = f2bs(f0.z); o[3] = f2bs(f0.w);
    o[4] = f2bs(f1v.x); o[5] = f2bs(f1v.y); o[6] = f2bs(f1v.z); o[7] = f2bs(f1v.w);
    *(short8*)((short*)dst + i) = o;
}

// ------------- embedding ------------------------------------------------------------
__global__ __launch_bounds__(256) void emb_kernel(const int* __restrict__ x,
    const float* __restrict__ tok, const float* __restrict__ pos, float* __restrict__ h)
{
    int i = blockIdx.x * 256 + threadIdx.x;
    int d = i & (DM - 1);
    int r = i >> 9;
    int t = r & (TSEQ - 1);
    h[i] = tok[x[r] * DM + d] + pos[t * DM + d];
}

// ------------- layernorm: wave per row, fp32 in, bf16 out ---------------------------
__global__ __launch_bounds__(256) void ln_kernel(const float* __restrict__ x,
    const float* __restrict__ w, const float* __restrict__ b, bf16* __restrict__ out)
{
    int row = blockIdx.x * 4 + (threadIdx.x >> 6);
    int lane = threadIdx.x & 63;
    const float* xr = x + (size_t)row * DM;

    float4 v0 = *(const float4*)(xr + lane * 4);
    float4 v1 = *(const float4*)(xr + 256 + lane * 4);

    float s = v0.x + v0.y + v0.z + v0.w + v1.x + v1.y + v1.z + v1.w;
    #pragma unroll
    for (int m = 1; m < 64; m <<= 1) s += __shfl_xor(s, m, 64);
    float mu = s * (1.f / DM);

    float var = (v0.x-mu)*(v0.x-mu) + (v0.y-mu)*(v0.y-mu) + (v0.z-mu)*(v0.z-mu)
              + (v0.w-mu)*(v0.w-mu) + (v1.x-mu)*(v1.x-mu) + (v1.y-mu)*(v1.y-mu)
              + (v1.z-mu)*(v1.z-mu) + (v1.w-mu)*(v1.w-mu);
    #pragma unroll
    for (int m = 1; m < 64; m <<= 1) var += __shfl_xor(var, m, 64);
    float rstd = rsqrtf(var * (1.f / DM) + 1e-5f);

    float4 w0 = *(const float4*)(w + lane * 4);
    float4 w1 = *(const float4*)(w + 256 + lane * 4);
    float4 b0 = *(const float4*)(b + lane * 4);
    float4 b1 = *(const float4*)(b + 256 + lane * 4);

    short4 o0, o1;
    o0.x = f2bs((v0.x - mu) * rstd * w0.x + b0.x);
    o0.y = f2bs((v0.y - mu) * rstd * w0.y + b0.y);
    o0.z = f2bs((v0.z - mu) * rstd * w0.z + b0.z);
    o0.w = f2bs((v0.w - mu) * rstd * w0.w + b0.w);
    o1.x = f2bs((v1.x - mu) * rstd * w1.x + b1.x);
    o1.y = f2bs((v1.y - mu) * rstd * w1.y + b1.y);
    o1.z = f2bs((v1.z - mu) * rstd * w1.z + b1.z);
    o1.w = f2bs((v1.w - mu) * rstd * w1.w + b1.w);
    *(short4*)(out + (size_t)row * DM + lane * 4) = o0;
    *(short4*)(out + (size_t)row * DM + 256 + lane * 4) = o1;
}

// ------------- MFMA GEMM 128x128, BK=64 as two concatenated 32-wide stages ----------
// EPI: 0 bf16 store, 1 fp32 +=, 2 GELU->bf16, 3 f32 store, 4 qkv split (Q|K|Vt)
template<int EPI, typename WT>
__global__ __launch_bounds__(256) void mfma_gemm(const bf16* __restrict__ A,
    const WT* __restrict__ W, void* __restrict__ Cv, int M, int N, int K)
{
    __shared__ short As[2][128 * 32];   // two 32-wide k-stages, proven layout each
    __shared__ short Bs[2][128 * 32];
    int tid = threadIdx.x;
    int bm0 = blockIdx.y * 128, bn0 = blockIdx.x * 128;
    int lane = tid & 63, w = tid >> 6;
    int wr = (w >> 1) * 64, wc = (w & 1) * 64;
    int fr = lane & 15, fk = (lane >> 4) * 8;

    f32x4 acc[4][4] = {};

    for (int k0 = 0; k0 < K; k0 += 64) {
        #pragma unroll
        for (int it = 0; it < 4; it++) {
            int c = it * 256 + tid;
            int buf = c >> 9, cp = c & 511;
            int row = cp >> 2, kc = (cp & 3) * 8;
            GLDS((const short*)A + (size_t)(bm0 + row) * K + k0 + buf * 32 + kc,
                 &As[0][0] + c * 8);
        }
        if constexpr (sizeof(WT) == 2) {
            #pragma unroll
            for (int it = 0; it < 4; it++) {
                int c = it * 256 + tid;
                int buf = c >> 9, cp = c & 511;
                int row = cp >> 2, kc = (cp & 3) * 8;
                GLDS((const short*)W + (size_t)(bn0 + row) * K + k0 + buf * 32 + kc,
                     &Bs[0][0] + c * 8);
            }
        } else {
            #pragma unroll
            for (int it = 0; it < 4; it++) {
                int c = it * 256 + tid;
                int buf = c >> 9, cp = c & 511;
                int row = cp >> 2, kc = (cp & 3) * 8;
                const float* wp = (const float*)W + (size_t)(bn0 + row) * K + k0 + buf * 32 + kc;
                float4 f0 = *(const float4*)wp;
                float4 f1 = *(const float4*)(wp + 4);
                short8 p;
                p[0] = f2bs(f0.x); p[1] = f2bs(f0.y); p[2] = f2bs(f0.z); p[3] = f2bs(f0.w);
                p[4] = f2bs(f1.x); p[5] = f2bs(f1.y); p[6] = f2bs(f1.z); p[7] = f2bs(f1.w);
                *(short8*)(&Bs[0][0] + c * 8) = p;
            }
        }
        __syncthreads();

        #pragma unroll
        for (int ks = 0; ks < 2; ks++) {
            short8 af[4], bfr[4];
            #pragma unroll
            for (int i = 0; i < 4; i++)
                af[i] = *(short8*)&As[ks][(wr + i * 16 + fr) * 32 + fk];
            #pragma unroll
            for (int j = 0; j < 4; j++)
                bfr[j] = *(short8*)&Bs[ks][(wc + j * 16 + fr) * 32 + fk];
            #pragma unroll
            for (int i = 0; i < 4; i++)
                #pragma unroll
                for (int j = 0; j < 4; j++)
                    acc[i][j] = __builtin_amdgcn_mfma_f32_16x16x32_bf16(
                        af[i], bfr[j], acc[i][j], 0, 0, 0);
        }
        __syncthreads();
    }

    int cr = (lane >> 4) * 4, cc = lane & 15;
    #pragma unroll
    for (int i = 0; i < 4; i++)
        #pragma unroll
        for (int j = 0; j < 4; j++)
            #pragma unroll
            for (int r = 0; r < 4; r++) {
                int m = bm0 + wr + i * 16 + cr + r;
                int n = bn0 + wc + j * 16 + cc;
                float v = acc[i][j][r];
                if (EPI == 4) {
                    // qkv split: Q | K row-major (stride 512), V transposed per head
                    short* q3s = (short*)Cv;
                    short sv = f2bs(v);
                    if (n < 512)
                        q3s[(size_t)m * 512 + n] = sv;
                    else if (n < 1024)
                        q3s[Q3_K_OFF + (size_t)m * 512 + (n - 512)] = sv;
                    else {
                        int bb = m >> 11, key = m & 2047;
                        int hd = (n - 1024) >> 6, dim = (n - 1024) & 63;
                        q3s[Q3_VT_OFF + (((size_t)(bb * 8 + hd) * 64 + dim) << 11) + key] = sv;
                    }
                } else {
                    size_t o = (size_t)m * N + n;
                    if (EPI == 0)      ((bf16*)Cv)[o] = __float2bfloat16(v);
                    else if (EPI == 1) ((float*)Cv)[o] += v;
                    else if (EPI == 2) ((bf16*)Cv)[o] =
                        __float2bfloat16(0.5f * v * (1.0f + erff(v * 0.70710678118654752f)));
                    else               ((float*)Cv)[o] = v;
                }
            }
}

// ------------- MFMA GEMM 128x64, BK=64 (narrow N: proj/fc2/head), B stride ldb ------
template<int EPI, typename WT>
__global__ __launch_bounds__(256) void mfma_gemm_n64(const bf16* __restrict__ A,
    const WT* __restrict__ W, void* __restrict__ Cv, int M, int N, int K, int ldb)
{
    __shared__ short As[2][128 * 32];
    __shared__ short Bs[2][64 * 32];
    int tid = threadIdx.x;
    int bm0 = blockIdx.y * 128, bn0 = blockIdx.x * 64;
    int lane = tid & 63, w = tid >> 6;
    int wm = (w & 1) * 64, wn = (w >> 1) * 32;
    int fr = lane & 15, fk = (lane >> 4) * 8;

    f32x4 acc[4][2] = {};

    for (int k0 = 0; k0 < K; k0 += 64) {
        #pragma unroll
        for (int it = 0; it < 4; it++) {
            int c = it * 256 + tid;
            int buf = c >> 9, cp = c & 511;
            int row = cp >> 2, kc = (cp & 3) * 8;
            GLDS((const short*)A + (size_t)(bm0 + row) * K + k0 + buf * 32 + kc,
                 &As[0][0] + c * 8);
        }
        if constexpr (sizeof(WT) == 2) {
            #pragma unroll
            for (int it = 0; it < 2; it++) {
                int c = it * 256 + tid;
                int buf = c >> 8, cp = c & 255;
                int row = cp >> 2, kc = (cp & 3) * 8;
                GLDS((const short*)W + (size_t)(bn0 + row) * ldb + k0 + buf * 32 + kc,
                     &Bs[0][0] + c * 8);
            }
        } else {
            #pragma unroll
            for (int it = 0; it < 2; it++) {
                int c = it * 256 + tid;
                int buf = c >> 8, cp = c & 255;
                int row = cp >> 2, kc = (cp & 3) * 8;
                const float* wp = (const float*)W + (size_t)(bn0 + row) * ldb + k0 + buf * 32 + kc;
                float4 f0 = *(const float4*)wp;
                float4 f1 = *(const float4*)(wp + 4);
                short8 p;
                p[0] = f2bs(f0.x); p[1] = f2bs(f0.y); p[2] = f2bs(f0.z); p[3] = f2bs(f0.w);
                p[4] = f2bs(f1.x); p[5] = f2bs(f1.y); p[6] = f2bs(f1.z); p[7] = f2bs(f1.w);
                *(short8*)(&Bs[0][0] + c * 8) = p;
            }
        }
        __syncthreads();

        #pragma unroll
        for (int ks = 0; ks < 2; ks++) {
            short8 af[4], bfr[2];
            #pragma unroll
            for (int i = 0; i < 4; i++)
                af[i] = *(short8*)&As[ks][(wm + i * 16 + fr) * 32 + fk];
            #pragma unroll
            for (int j = 0; j < 2; j++)
                bfr[j] = *(short8*)&Bs[ks][(wn + j * 16 + fr) * 32 + fk];
            #pragma unroll
            for (int i = 0; i < 4; i++)
                #pragma unroll
                for (int j = 0; j < 2; j++)
                    acc[i][j] = __builtin_amdgcn_mfma_f32_16x16x32_bf16(
                        af[i], bfr[j], acc[i][j], 0, 0, 0);
        }
        __syncthreads();
    }

    int cr = (lane >> 4) * 4, cc = lane & 15;
    #pragma unroll
    for (int i = 0; i < 4; i++)
        #pragma unroll
        for (int j = 0; j < 2; j++)
            #pragma unroll
            for (int r = 0; r < 4; r++) {
                int m = bm0 + wm + i * 16 + cr + r;
                int n = bn0 + wn + j * 16 + cc;
                size_t o = (size_t)m * N + n;
                float v = acc[i][j][r];
                if (EPI == 0)      ((bf16*)Cv)[o] = __float2bfloat16(v);
                else if (EPI == 1) ((float*)Cv)[o] += v;
                else if (EPI == 2) ((bf16*)Cv)[o] =
                    __float2bfloat16(0.5f * v * (1.0f + erff(v * 0.70710678118654752f)));
                else               ((float*)Cv)[o] = v;
            }
}

// ------------- MFMA flash attention (r12-exact: 50.1 us proven) ---------------------
// Block = 64 queries (4 waves x 16-row strips), k-tile 128, balanced qt,
// fixed-m softmax, staged LDS with r12's paired-chunk staging (VGPR 124).
__device__ __forceinline__ int pswz(int row, int col) {    // P strip: 16-chunk perm
    return row * 136 + ((((col >> 3) + row) & 15) << 3) + (col & 7);
}

__global__ __launch_bounds__(256) void fattn_kernel(const short* __restrict__ q3,
    bf16* __restrict__ out)
{
    __shared__ __align__(16) short Ks[128 * 72];     // [key][dim], pad 8
    __shared__ __align__(16) short Vt[64 * 136];     // [dim][key], pad 8
    __shared__ __align__(16) short Ps[4][16 * 136];  // per-wave P strip (pswz)

    int tid = threadIdx.x;
    int lane = tid & 63, w = tid >> 6;
    int quad = lane >> 4, cl = lane & 15;
    int bh = blockIdx.y;                     // b*8 + hd
    int b = bh >> 3, hd = bh & 7;
    int bx = blockIdx.x;                     // 0..31
    int qt = b ? bx : (31 - bx);             // balance across CU block pairs
    int q0 = qt * 64;
    const short* Qb = q3;
    const short* Kb = q3 + Q3_K_OFF + (size_t)b * 2048 * 512 + hd * 64;
    const short* Vb = q3 + Q3_VT_OFF + (size_t)bh * 64 * 2048;
    short* Pw = &Ps[w][0];

    short8 qf[2];
    {
        const short* qrow = Qb + (size_t)(b * 2048 + q0 + w * 16 + cl) * 512 + hd * 64;
        qf[0] = *(const short8*)(qrow + quad * 8);
        qf[1] = *(const short8*)(qrow + 32 + quad * 8);
    }

    float l_r[4] = {0.f, 0.f, 0.f, 0.f};
    f32x4 o_acc[4] = {};

    int nkt = (q0 + 64 + 127) >> 7;

    for (int kt = 0; kt < nkt; kt++) {
        int k0 = kt * 128;
        __syncthreads();   // previous tile fully consumed
        // ---- stage K [128][64]: r12 paired-chunk pattern ----
        #pragma unroll
        for (int it = 0; it < 2; it++) {
            int c = it * 512 + tid * 2;      // 2 consecutive chunks per thread
            int row = c >> 3, cc = c & 7;
            const short* src = Kb + (size_t)(k0 + row) * 512 + cc * 8;
            *(short8*)&Ks[row * 72 + cc * 8] = *(const short8*)src;
            *(short8*)&Ks[row * 72 + cc * 8 + 8] = *(const short8*)(src + 8);
        }
        // ---- stage Vt [64][128]: coalesced rows (keys contiguous) ----
        #pragma unroll
        for (int it = 0; it < 2; it++) {
            int c = it * 512 + tid * 2;
            int row = c >> 4, cc = c & 15;
            const short* src = Vb + (size_t)row * 2048 + k0 + cc * 8;
            *(short8*)&Vt[row * 136 + cc * 8] = *(const short8*)src;
            *(short8*)&Vt[row * 136 + cc * 8 + 8] = *(const short8*)(src + 8);
        }
        __syncthreads();

        // ---- S strip = Q·K^T (16 x 128) ----
        f32x4 s[8];
        #pragma unroll
        for (int j = 0; j < 8; j++) {
            int key = j * 16 + cl;
            short8 kf0 = *(short8*)&Ks[key * 72 + quad * 8];
            short8 kf1 = *(short8*)&Ks[key * 72 + 32 + quad * 8];
            f32x4 a = {};
            a = __builtin_amdgcn_mfma_f32_16x16x32_bf16(qf[0], kf0, a, 0, 0, 0);
            a = __builtin_amdgcn_mfma_f32_16x16x32_bf16(qf[1], kf1, a, 0, 0, 0);
            s[j] = a;
        }

        // ---- scale + mask + exp (fixed-m: scores are O(1)) ----
        int grow = q0 + w * 16 + quad * 4;
        bool last = (kt == nkt - 1);
        #pragma unroll
        for (int j = 0; j < 8; j++)
            #pragma unroll
            for (int r = 0; r < 4; r++) {
                bool masked = last && (k0 + j * 16 + cl) > (grow + r);
                float p = masked ? 0.f : __expf(s[j][r] * 0.125f);
                s[j][r] = p;
                l_r[r] += p;
            }

        // ---- P (C layout) -> wave-local LDS -> A layout (no barrier: wave-local) ----
        #pragma unroll
        for (int j = 0; j < 8; j++) {
            int key = j * 16 + cl;
            #pragma unroll
            for (int r = 0; r < 4; r++)
                Pw[pswz(quad * 4 + r, key)] = f2bs(s[j][r]);
        }
        short8 pf[4];
        #pragma unroll
        for (int c = 0; c < 4; c++)
            pf[c] = *(short8*)&Pw[pswz(cl, c * 32 + quad * 8)];

        // ---- O += P·V ----
        #pragma unroll
        for (int j = 0; j < 4; j++) {
            int dim = j * 16 + cl;
            #pragma unroll
            for (int c = 0; c < 4; c++) {
                short8 vf = *(short8*)&Vt[dim * 136 + c * 32 + quad * 8];
                o_acc[j] = __builtin_amdgcn_mfma_f32_16x16x32_bf16(
                    pf[c], vf, o_acc[j], 0, 0, 0);
            }
        }
    }

    // ---- epilogue: one l-reduction per row, then O/l ----
    int grow = q0 + w * 16 + quad * 4;
    #pragma unroll
    for (int r = 0; r < 4; r++) {
        float l = l_r[r];
        #pragma unroll
        for (int m = 1; m < 16; m <<= 1) l += __shfl_xor(l, m, 64);
        float inv = 1.f / l;
        #pragma unroll
        for (int j = 0; j < 4; j++)
            out[(size_t)(b * TSEQ + grow + r) * DM + hd * DH + j * 16 + cl] =
                __float2bfloat16(o_acc[j][r] * inv);
    }
}

// ------------- host-side model driver, templated on weight dtype --------------------
template<typename WT>
static void run_model(const int* x, const float* tok, const float* pos,
    const WT* qkvw, const WT* projw,
    const float* ln1w, const float* ln1b, const float* ln2w, const float* ln2b,
    const WT* fc1w, const WT* fc2w, const float* lnfw, const float* lnfb,
    const WT* headw, float* h, bf16* xn, bf16* q3, bf16* hid16,
    float* dout, hipStream_t stream)
{
    emb_kernel<<<ROWS * DM / 256, 256, 0, stream>>>(x, tok, pos, h);

    for (int l = 0; l < DEPTH; l++) {
        ln_kernel<<<ROWS / 4, 256, 0, stream>>>(h, ln1w + l * DM, ln1b + l * DM, xn);
        mfma_gemm<4, WT><<<dim3(3 * DM / 128, ROWS / 128), 256, 0, stream>>>(
            xn, qkvw + (size_t)l * 3 * DM * DM, q3, ROWS, 3 * DM, DM);
        fattn_kernel<<<dim3(TSEQ / 64, BATCH * NH), 256, 0, stream>>>((short*)q3, xn);
        mfma_gemm_n64<1, WT><<<dim3(DM / 64, ROWS / 128), 256, 0, stream>>>(
            xn, projw + (size_t)l * DM * DM, h, ROWS, DM, DM, DM);
        ln_kernel<<<ROWS / 4, 256, 0, stream>>>(h, ln2w + l * DM, ln2b + l * DM, xn);
        if (hid16) {
            // fused MLP: fc1 full N=2048, fc2 single K=2048
            mfma_gemm<2, WT><<<dim3(DFF / 128, ROWS / 128), 256, 0, stream>>>(
                xn, fc1w + (size_t)l * DFF * DM, hid16, ROWS, DFF, DM);
            mfma_gemm_n64<1, WT><<<dim3(DM / 64, ROWS / 128), 256, 0, stream>>>(
                hid16, fc2w + (size_t)l * DM * DFF, h, ROWS, DM, DFF, DFF);
        } else {
            for (int p = 0; p < 2; p++) {
                mfma_gemm<2, WT><<<dim3(1024 / 128, ROWS / 128), 256, 0, stream>>>(
                    xn, fc1w + (size_t)l * DFF * DM + (size_t)p * 1024 * DM,
                    q3, ROWS, 1024, DM);
                mfma_gemm_n64<1, WT><<<dim3(DM / 64, ROWS / 128), 256, 0, stream>>>(
                    q3, fc2w + (size_t)l * DM * DFF + (size_t)p * 1024,
                    h, ROWS, DM, 1024, DFF);
            }
        }
    }

    ln_kernel<<<ROWS / 4, 256, 0, stream>>>(h, lnfw, lnfb, xn);
    mfma_gemm_n64<3, WT><<<dim3(NVOCAB / 64, ROWS / 128), 256, 0, stream>>>(
        xn, headw, dout, ROWS, NVOCAB, DM, DM);
}

extern "C" void kernel_launch(void* const* d_in, const int* in_sizes, int n_in,
                              void* d_out, int out_size, void* d_ws, size_t ws_size,
                              hipStream_t stream)
{
    const int*   x     = (const int*)d_in[0];
    const float* tok   = (const float*)d_in[1];
    const float* pos   = (const float*)d_in[2];
    const float* qkvw  = (const float*)d_in[3];
    const float* projw = (const float*)d_in[4];
    const float* ln1w  = (const float*)d_in[5];
    const float* ln1b  = (const float*)d_in[6];
    const float* ln2w  = (const float*)d_in[7];
    const float* ln2b  = (const float*)d_in[8];
    const float* fc1w  = (const float*)d_in[9];
    const float* fc2w  = (const float*)d_in[10];
    const float* lnfw  = (const float*)d_in[11];
    const float* lnfb  = (const float*)d_in[12];
    const float* headw = (const float*)d_in[13];

    // ws: h fp32 @0 (8 MiB) | xn bf16 @8MiB (4 MiB) | q3 @12MiB (12 MiB)
    // | bf16 weights @24MiB (~36.3 MiB) | hidden16 bf16 [4096,2048] (16 MiB) if room.
    char* ws = (char*)d_ws;
    float* h  = (float*)ws;
    bf16*  xn = (bf16*)(ws + (8u << 20));
    bf16*  q3 = (bf16*)(ws + (12u << 20));

    const size_t wb_off = (size_t)24 << 20;
    const size_t hid_off = wb_off + 2 * SZ_ALL;
    const size_t need1 = hid_off;                       // bf16 weights, split MLP
    const size_t need2 = hid_off + ((size_t)16 << 20);  // + fused MLP hidden

    if (ws_size >= need1) {
        bf16* wb = (bf16*)(ws + wb_off);
        bf16* hid16 = (ws_size >= need2) ? (bf16*)(ws + hid_off) : (bf16*)nullptr;
        w2b_all<<<SZ_ALL / 2048, 256, 0, stream>>>(qkvw, projw, fc1w, fc2w, headw, wb);
        const bf16* qkvwb  = wb;
        const bf16* projwb = qkvwb + SZ_QKV;
        const bf16* fc1wb  = projwb + SZ_PROJ;
        const bf16* fc2wb  = fc1wb + SZ_FC1;
        const bf16* headwb = fc2wb + SZ_FC2;
        run_model<bf16>(x, tok, pos, qkvwb, projwb, ln1w, ln1b, ln2w, ln2b,
                        fc1wb, fc2wb, lnfw, lnfb, headwb,
                        h, xn, q3, hid16, (float*)d_out, stream);
    } else {
        run_model<float>(x, tok, pos, qkvw, projw, ln1w, ln1b, ln2w, ln2b,
                         fc1w, fc2w, lnfw, lnfb, headw,
                         h, xn, q3, (bf16*)nullptr, (float*)d_out, stream);
    }
}